// Round 10
// baseline (509.114 us; speedup 1.0000x reference)
//
#include <hip/hip_runtime.h>
#include <hip/hip_bf16.h>

#define NTOK 8192      // B*T
#define CDIM 256
#define TDIM 2048
#define BDIM 4
#define HDIM 8
#define HSZ  32
#define LNUM 4
#define BUF  (NTOK*CDIM)
#define QSTR 768       // fused qkv row stride
#define LC   0.0901684400056f   // 2^-4 * log2(e), folded into Wq/bq

typedef __attribute__((ext_vector_type(8))) short short8v;
typedef __attribute__((ext_vector_type(4))) short short4v;
typedef __attribute__((ext_vector_type(4))) float float4v;

// ---- fp32 -> bf16 pack helpers ----
#if __has_builtin(__builtin_amdgcn_cvt_pk_bf16_f32)
static __device__ __forceinline__ unsigned pkbf(float a, float b){
  auto t = __builtin_amdgcn_cvt_pk_bf16_f32(a, b);
  union { decltype(t) v; unsigned u; } cv; cv.v = t;
  return cv.u;
}
static __device__ __forceinline__ short f2bs(float f){
  auto t = __builtin_amdgcn_cvt_pk_bf16_f32(f, f);
  union { decltype(t) v; unsigned u; } cv; cv.v = t;
  return (short)(cv.u & 0xFFFFu);
}
#else
static __device__ __forceinline__ short f2bs(float f){
  union { float f; unsigned u; } x; x.f = f;
  unsigned r = x.u + 0x7FFFu + ((x.u >> 16) & 1u);
  return (short)(r >> 16);
}
static __device__ __forceinline__ unsigned pkbf(float a, float b){
  union { float f; unsigned u; } x, y; x.f = a; y.f = b;
  unsigned ra = x.u + 0x7FFFu + ((x.u >> 16) & 1u);
  unsigned rb = y.u + 0x7FFFu + ((y.u >> 16) & 1u);
  return __builtin_amdgcn_perm(rb, ra, 0x07060302u);
}
#endif
#if __has_builtin(__builtin_amdgcn_exp2f)
static __device__ __forceinline__ float fexp2(float x){ return __builtin_amdgcn_exp2f(x); }
#else
static __device__ __forceinline__ float fexp2(float x){ return __expf(x*0.6931471805599453f); }
#endif

#if __has_builtin(__builtin_amdgcn_mfma_f32_16x16x16bf16_1k)
static __device__ __forceinline__ float4v mfma16(short4v a, short4v b, float4v c){
  return __builtin_amdgcn_mfma_f32_16x16x16bf16_1k(a, b, c, 0, 0, 0);
}
#else
static __device__ __forceinline__ float4v mfma16(short4v a, short4v b, float4v c){
  float4v d;
  asm volatile("v_mfma_f32_16x16x16_bf16 %0, %1, %2, %3\n\ts_nop 7\n\ts_nop 7"
               : "=v"(d) : "v"(a), "v"(b), "v"(c));
  return d;
}
#endif
static __device__ __forceinline__ float4v mfma32(short8v a, short8v b, float4v c){
  return __builtin_amdgcn_mfma_f32_16x16x32_bf16(a, b, c, 0, 0, 0);
}

// fragment-packed weight address: value (n,k) -> cg=n>>4, ks=k>>5, lane=((k>>3)&3)*16+(n&15), j=k&7
static __device__ __forceinline__ int faddr(int n, int k){
  return ((n>>4)*8 + (k>>5))*512 + ((((k>>3)&3)<<4) + (n&15))*8 + (k&7);
}

// ---------------- merged weight prep + bias folding + embedding + LN1(layer0) ----------------
__global__ __launch_bounds__(256) void k_prep_embed(
    const int* __restrict__ idx, const float* __restrict__ tok, const float* __restrict__ pos,
    const float* __restrict__ Wq, const float* __restrict__ Wk, const float* __restrict__ Wv,
    const float* __restrict__ Wp, const float* __restrict__ W1, const float* __restrict__ W2,
    const float* __restrict__ l1g, const float* __restrict__ l2g,
    const float* __restrict__ l1b, const float* __restrict__ l2b,
    const float* __restrict__ b1, const float* __restrict__ Wc1, const float* __restrict__ lnfg,
    const float* __restrict__ lnfb, const float* __restrict__ bc1,
    short* __restrict__ qkvT, short* __restrict__ wpT, short* __restrict__ w1T, short* __restrict__ w2T,
    float* __restrict__ bq, float* __restrict__ b1f, float* __restrict__ Wc1s, float* __restrict__ bc1f,
    float* __restrict__ x, short* __restrict__ y) {
  const int tid = threadIdx.x;
  const int id = blockIdx.x;
  if (id >= 513) {
    // ---- embedding + LN path ----
    const int bid = id - 513;
    const int lane = tid & 63;
    const int bt = bid*4 + (tid >> 6);
    const int t = bt & (TDIM-1);
    float4 tv = *(const float4*)&tok[(size_t)idx[bt]*CDIM + lane*4];
    float4 pv = *(const float4*)&pos[(size_t)t*CDIM + lane*4];
    float4 v = make_float4(tv.x+pv.x, tv.y+pv.y, tv.z+pv.z, tv.w+pv.w);
    *(float4*)&x[(size_t)bt*CDIM + lane*4] = v;
    float s1 = (v.x+v.y) + (v.z+v.w);
    float s2 = fmaf(v.x,v.x, fmaf(v.y,v.y, fmaf(v.z,v.z, v.w*v.w)));
    #pragma unroll
    for (int off=32; off>0; off>>=1) { s1 += __shfl_xor(s1, off, 64); s2 += __shfl_xor(s2, off, 64); }
    float mean = s1*(1.f/CDIM);
    float inv  = rsqrtf(s2*(1.f/CDIM) - mean*mean + 1e-5f);
    float cc = -mean*inv;
    union { unsigned u[2]; short4v s; } o;
    o.u[0] = pkbf(fmaf(v.x,inv,cc), fmaf(v.y,inv,cc));
    o.u[1] = pkbf(fmaf(v.z,inv,cc), fmaf(v.w,inv,cc));
    *(short4v*)&y[(size_t)bt*CDIM + lane*4] = o.s;
    return;
  }
  if (id < 384) {
    __shared__ float tile[64][65];
    int l = id / 96, rr = id % 96;
    const float* src; short* dst; int n0, k0; bool qkvmode; int gsel; float nscale = 1.f;
    if (rr < 48) {
      int tn = rr >> 2, tk = rr & 3;
      n0 = tn*64; k0 = tk*64;
      const float* b3 = (n0 < 256) ? Wq : (n0 < 512 ? Wk : Wv);
      src = b3 + l*65536;
      dst = qkvT + (size_t)l*QSTR*256;
      qkvmode = true; gsel = 1;
      if (n0 < 256) nscale = LC;
    } else {
      int r2 = rr - 48;
      int mat = r2 >> 4, t = r2 & 15;
      int tn = t >> 2, tk = t & 3;
      n0 = tn*64; k0 = tk*64;
      const float* b3 = (mat == 0) ? Wp : (mat == 1 ? W1 : W2);
      src = b3 + l*65536;
      dst = (mat == 0 ? wpT : (mat == 1 ? w1T : w2T)) + l*65536;
      qkvmode = false; gsel = (mat == 1) ? 2 : 0;
    }
    const int cn = tid & 63, rk = tid >> 6;
    #pragma unroll
    for (int i = 0; i < 16; ++i) {
      int kk = rk + i*4;
      int n = n0 + cn, k = k0 + kk;
      float v;
      if (qkvmode) { int nn = n & 255; v = src[((nn>>5)*256 + k)*32 + (nn & 31)]; }
      else         { v = src[k*256 + n]; }
      if (gsel == 1)      v *= l1g[l*256 + k];
      else if (gsel == 2) v *= l2g[l*256 + k];
      tile[kk][cn] = v;
    }
    __syncthreads();
    #pragma unroll
    for (int i = 0; i < 16; ++i) {
      int nn = rk + i*4;
      dst[faddr(n0 + nn, k0 + cn)] = f2bs(tile[cn][nn] * nscale);
    }
  } else if (id < 448) {
    __shared__ float red[4][64];
    int bid = id - 384;
    int l = bid >> 4, seg = bid & 15;
    int o = seg*64 + (tid & 63), pp = tid >> 6;
    float s = 0.f;
    if (o < 768) {
      const float* W = (o < 256 ? Wq : (o < 512 ? Wk : Wv)) + l*65536;
      int nn = o & 255, h = nn >> 5, d = nn & 31;
      const float* bv = l1b + l*256;
      for (int k = pp*64; k < pp*64+64; ++k) s = fmaf(bv[k], W[(h*256 + k)*32 + d], s);
    } else {
      const float* W = W1 + l*65536;
      int n = o - 768;
      const float* bv = l2b + l*256;
      for (int k = pp*64; k < pp*64+64; ++k) s = fmaf(bv[k], W[k*256 + n], s);
    }
    red[pp][tid & 63] = s;
    __syncthreads();
    if (tid < 64) {
      float tot = red[0][tid]+red[1][tid]+red[2][tid]+red[3][tid];
      int oo = seg*64 + tid;
      if (oo < 768) bq[l*768 + oo] = tot * (oo < 256 ? LC : 1.f);
      else          b1f[l*256 + (oo-768)] = b1[l*256 + (oo-768)] + tot;
    }
  } else if (id < 512) {
    int base = (id-448)*2048;
    #pragma unroll
    for (int i=0;i<8;++i) {
      int idx2 = base + i*256 + tid;
      Wc1s[idx2] = Wc1[idx2] * lnfg[idx2 >> 9];
    }
  } else {
    for (int u = tid; u < 512; u += 256) {
      float s = bc1[u];
      for (int k=0;k<256;++k) s = fmaf(lnfb[k], Wc1[k*512+u], s);
      bc1f[u] = s;
    }
  }
}

// ---------------- LDS-free MFMA GEMM (QKV layer 0): C = A(bf16) x Bfrag(packed) ----------------
template<int NF, bool BIAS, bool RELU, bool OUTBF16, bool ACCUM>
__global__ __launch_bounds__(64) void k_gemm3(const short* __restrict__ A,
    const short* __restrict__ Bt, const float* __restrict__ bias, void* __restrict__ Cv,
    int outstride) {
  const int lane = threadIdx.x;
  const int q4 = lane >> 4, r = lane & 15;
  const int blockRow = blockIdx.x * 32;
  const int blockCol = blockIdx.y * (NF*16);
  float4v acc[2][NF];
  #pragma unroll
  for (int i=0;i<2;++i)
    #pragma unroll
    for (int j=0;j<NF;++j) acc[i][j] = (float4v){0,0,0,0};
  #pragma unroll
  for (int k0 = 0; k0 < 256; k0 += 32) {
    short8v a0 = *(const short8v*)&A[(size_t)(blockRow +      r)*CDIM + k0 + q4*8];
    short8v a1 = *(const short8v*)&A[(size_t)(blockRow + 16 + r)*CDIM + k0 + q4*8];
    #pragma unroll
    for (int nf=0; nf<NF; ++nf) {
      short8v bf = *(const short8v*)&Bt[(size_t)(((blockCol>>4) + nf)*8 + (k0>>5))*512 + lane*8];
      acc[0][nf] = mfma32(a0, bf, acc[0][nf]);
      acc[1][nf] = mfma32(a1, bf, acc[1][nf]);
    }
  }
  #pragma unroll
  for (int mf=0; mf<2; ++mf)
    #pragma unroll
    for (int nf=0; nf<NF; ++nf) {
      int col = blockCol + nf*16 + r;
      float bb = BIAS ? bias[col] : 0.f;
      #pragma unroll
      for (int reg=0; reg<4; ++reg) {
        int row = blockRow + mf*16 + q4*4 + reg;
        float v = acc[mf][nf][reg] + bb;
        if (RELU) v = fmaxf(v, 0.f);
        size_t oi = (size_t)row*outstride + col;
        if (ACCUM)        ((float*)Cv)[oi] += v;
        else if (OUTBF16) ((short*)Cv)[oi] = f2bs(v);
        else              ((float*)Cv)[oi] = v;
      }
    }
}

// ---------------- fused per-layer MLP: proj+res+LN1 -> FFN -> res+LN2 -> next-layer QKV ------
template<bool LAST>
__global__ __launch_bounds__(1024, 4) void k_mlp(
    const short* __restrict__ A,            // attn output rows (bf16, stride CDIM)
    const short* __restrict__ Bt,           // wpT layer l (fragment-packed)
    const float* __restrict__ bias,         // bproj layer l
    const short* __restrict__ W1t, const float* __restrict__ b1f,
    const short* __restrict__ W2t, const float* __restrict__ b2,
    float* __restrict__ X,                  // fp32 residual stream
    const short* __restrict__ Wqkv,         // qkvT layer l+1 (fragment-packed; unused if LAST)
    const float* __restrict__ bq,           // bq layer l+1   (unused if LAST)
    short* __restrict__ Qout) {             // qkvb           (unused if LAST)
  __shared__ __align__(16) short Ys[32*264];
  __shared__ __align__(16) short Gs[32*264];
  __shared__ float S1[32][16], S2[32][16];
  const int tid = threadIdx.x;
  const int w = tid >> 6, lane = tid & 63;
  const int q4 = lane >> 4, r = lane & 15;
  const int row0 = blockIdx.x * 32;
  const int colw = w*16 + r;               // this wave's output column, phases A/B

  // ===== stage A tile (32x256 bf16 = 16KB) into Gs, fully coalesced =====
  {
    short8v av = *(const short8v*)&A[(size_t)row0*CDIM + tid*8];
    *(short8v*)&Gs[(tid>>5)*264 + (tid&31)*8] = av;
  }
  __syncthreads();

  // ===== Phase A: proj GEMM (A from LDS, B packed) =====
  float4v acc0 = {0,0,0,0}, acc1 = {0,0,0,0};
  #pragma unroll
  for (int k=0;k<8;++k) {
    short8v b  = *(const short8v*)&Bt[(size_t)(w*8+k)*512 + lane*8];
    short8v a0 = *(const short8v*)&Gs[(     r)*264 + k*32 + q4*8];
    short8v a1 = *(const short8v*)&Gs[(16 + r)*264 + k*32 + q4*8];
    acc0 = mfma32(a0, b, acc0);
    acc1 = mfma32(a1, b, acc1);
  }
  float xv0[4], xv1[4];
  {
    float bb = bias[colw];
    #pragma unroll
    for (int reg=0; reg<4; ++reg) {
      float t0 = acc0[reg] + bb + X[(size_t)(row0 +      q4*4 + reg)*CDIM + colw];
      float t1 = acc1[reg] + bb + X[(size_t)(row0 + 16 + q4*4 + reg)*CDIM + colw];
      xv0[reg] = t0; xv1[reg] = t1;
      float s10 = t0, s20 = t0*t0, s11 = t1, s21 = t1*t1;
      #pragma unroll
      for (int off=1; off<16; off<<=1) {
        s10 += __shfl_xor(s10, off, 64); s20 += __shfl_xor(s20, off, 64);
        s11 += __shfl_xor(s11, off, 64); s21 += __shfl_xor(s21, off, 64);
      }
      if (r == 0) {
        S1[     q4*4 + reg][w] = s10; S2[     q4*4 + reg][w] = s20;
        S1[16 + q4*4 + reg][w] = s11; S2[16 + q4*4 + reg][w] = s21;
      }
    }
  }
  __syncthreads();
  // LN1 -> Ys
  #pragma unroll
  for (int reg=0; reg<4; ++reg) {
    int r0i = q4*4 + reg, r1i = 16 + q4*4 + reg;
    float s1=0.f, s2=0.f, t1=0.f, t2=0.f;
    #pragma unroll
    for (int j=0;j<16;++j) { s1 += S1[r0i][j]; s2 += S2[r0i][j]; t1 += S1[r1i][j]; t2 += S2[r1i][j]; }
    float mean = s1*(1.f/CDIM);
    float inv  = rsqrtf(s2*(1.f/CDIM) - mean*mean + 1e-5f);
    Ys[r0i*264 + colw] = f2bs(fmaf(xv0[reg], inv, -mean*inv));
    float mean2 = t1*(1.f/CDIM);
    float inv2  = rsqrtf(t2*(1.f/CDIM) - mean2*mean2 + 1e-5f);
    Ys[r1i*264 + colw] = f2bs(fmaf(xv1[reg], inv2, -mean2*inv2));
  }
  __syncthreads();

  // ===== FFN1: A from Ys, B packed -> relu -> Gs =====
  acc0 = (float4v){0,0,0,0}; acc1 = (float4v){0,0,0,0};
  #pragma unroll
  for (int k=0;k<8;++k) {
    short8v b  = *(const short8v*)&W1t[(size_t)(w*8+k)*512 + lane*8];
    short8v a0 = *(const short8v*)&Ys[(     r)*264 + k*32 + q4*8];
    short8v a1 = *(const short8v*)&Ys[(16 + r)*264 + k*32 + q4*8];
    acc0 = mfma32(a0, b, acc0);
    acc1 = mfma32(a1, b, acc1);
  }
  {
    float g = b1f[colw];
    #pragma unroll
    for (int reg=0; reg<4; ++reg) {
      Gs[(     q4*4 + reg)*264 + colw] = f2bs(fmaxf(acc0[reg] + g, 0.f));
      Gs[(16 + q4*4 + reg)*264 + colw] = f2bs(fmaxf(acc1[reg] + g, 0.f));
    }
  }
  __syncthreads();

  // ===== FFN2: A from Gs, B packed + residual [+ LN2 -> Ys] =====
  acc0 = (float4v){0,0,0,0}; acc1 = (float4v){0,0,0,0};
  #pragma unroll
  for (int k=0;k<8;++k) {
    short8v b  = *(const short8v*)&W2t[(size_t)(w*8+k)*512 + lane*8];
    short8v a0 = *(const short8v*)&Gs[(     r)*264 + k*32 + q4*8];
    short8v a1 = *(const short8v*)&Gs[(16 + r)*264 + k*32 + q4*8];
    acc0 = mfma32(a0, b, acc0);
    acc1 = mfma32(a1, b, acc1);
  }
  {
    float bb2 = b2[colw];
    #pragma unroll
    for (int reg=0; reg<4; ++reg) {
      float t0 = acc0[reg] + bb2 + xv0[reg];
      float t1 = acc1[reg] + bb2 + xv1[reg];
      xv0[reg] = t0; xv1[reg] = t1;
      X[(size_t)(row0 +      q4*4 + reg)*CDIM + colw] = t0;
      X[(size_t)(row0 + 16 + q4*4 + reg)*CDIM + colw] = t1;
      if (!LAST) {
        float s10 = t0, s20 = t0*t0, s11 = t1, s21 = t1*t1;
        #pragma unroll
        for (int off=1; off<16; off<<=1) {
          s10 += __shfl_xor(s10, off, 64); s20 += __shfl_xor(s20, off, 64);
          s11 += __shfl_xor(s11, off, 64); s21 += __shfl_xor(s21, off, 64);
        }
        if (r == 0) {
          S1[     q4*4 + reg][w] = s10; S2[     q4*4 + reg][w] = s20;
          S1[16 + q4*4 + reg][w] = s11; S2[16 + q4*4 + reg][w] = s21;
        }
      }
    }
  }
  if (LAST) return;
  __syncthreads();
  // LN2 -> Ys
  #pragma unroll
  for (int reg=0; reg<4; ++reg) {
    int r0i = q4*4 + reg, r1i = 16 + q4*4 + reg;
    float s1=0.f, s2=0.f, t1=0.f, t2=0.f;
    #pragma unroll
    for (int j=0;j<16;++j) { s1 += S1[r0i][j]; s2 += S2[r0i][j]; t1 += S1[r1i][j]; t2 += S2[r1i][j]; }
    float mean = s1*(1.f/CDIM);
    float inv  = rsqrtf(s2*(1.f/CDIM) - mean*mean + 1e-5f);
    Ys[r0i*264 + colw] = f2bs(fmaf(xv0[reg], inv, -mean*inv));
    float mean2 = t1*(1.f/CDIM);
    float inv2  = rsqrtf(t2*(1.f/CDIM) - mean2*mean2 + 1e-5f);
    Ys[r1i*264 + colw] = f2bs(fmaf(xv1[reg], inv2, -mean2*inv2));
  }
  __syncthreads();

  // ===== Phase C: next-layer QKV GEMM (A from Ys, B packed), wave = 32 rows x 48 cols =====
  {
    float4v qa0[3], qa1[3];
    #pragma unroll
    for (int j=0;j<3;++j) { qa0[j] = (float4v){0,0,0,0}; qa1[j] = (float4v){0,0,0,0}; }
    #pragma unroll
    for (int k=0;k<8;++k) {
      short8v ay0 = *(const short8v*)&Ys[(     r)*264 + k*32 + q4*8];
      short8v ay1 = *(const short8v*)&Ys[(16 + r)*264 + k*32 + q4*8];
      #pragma unroll
      for (int nf=0; nf<3; ++nf) {
        short8v b = *(const short8v*)&Wqkv[(size_t)((w*3+nf)*8 + k)*512 + lane*8];
        qa0[nf] = mfma32(ay0, b, qa0[nf]);
        qa1[nf] = mfma32(ay1, b, qa1[nf]);
      }
    }
    #pragma unroll
    for (int nf=0; nf<3; ++nf) {
      int col = (w*3+nf)*16 + r;
      float bb = bq[col];
      #pragma unroll
      for (int reg=0; reg<4; ++reg) {
        Qout[(size_t)(row0 +      q4*4 + reg)*QSTR + col] = f2bs(qa0[nf][reg] + bb);
        Qout[(size_t)(row0 + 16 + q4*4 + reg)*QSTR + col] = f2bs(qa1[nf][reg] + bb);
      }
    }
  }
}

// ---------------- MFMA flash attention: 128-key tiles, dbuf, 64 q-rows/block ----------------
#define KSS 40
#define VTS 140
__global__ __launch_bounds__(256, 4) void k_attn6(const short* __restrict__ qkv,
    short* __restrict__ O) {
  __shared__ __align__(16) short Ks[2][128*KSS];
  __shared__ __align__(16) short Vt[2][32*VTS];
  const int tid = threadIdx.x;
  const int w = tid >> 6, lane = tid & 63;
  const int q4 = lane >> 4, r = lane & 15;
  const int b = blockIdx.z, h = blockIdx.y;
  const int rowbase = blockIdx.x*64 + w*16;
  short8v Qf = *(const short8v*)&qkv[((size_t)(b*TDIM + rowbase + r))*QSTR + h*HSZ + q4*8];
  float4v o0 = {0,0,0,0}, o1 = {0,0,0,0};
  float l0 = 0.f;
  const bool isV = tid >= 128;
  const int t2 = tid & 127;
  const int kp = t2 & 63, dgb = t2 >> 6;   // V loader: dg in {dgb, dgb+2}
  const short* kvbase = qkv + (size_t)b*TDIM*QSTR + h*HSZ;
  short8v ka0, ka1, ka2, ka3;              // K loader: full 32-d row of key t2
  short8v va0, vb0, va1, vb1;
  if (isV) {
    va0 = *(const short8v*)&kvbase[(size_t)(2*kp)*QSTR   + 2*CDIM + dgb*8];
    vb0 = *(const short8v*)&kvbase[(size_t)(2*kp+1)*QSTR + 2*CDIM + dgb*8];
    va1 = *(const short8v*)&kvbase[(size_t)(2*kp)*QSTR   + 2*CDIM + (dgb+2)*8];
    vb1 = *(const short8v*)&kvbase[(size_t)(2*kp+1)*QSTR + 2*CDIM + (dgb+2)*8];
  } else {
    ka0 = *(const short8v*)&kvbase[(size_t)t2*QSTR + CDIM +  0];
    ka1 = *(const short8v*)&kvbase[(size_t)t2*QSTR + CDIM +  8];
    ka2 = *(const short8v*)&kvbase[(size_t)t2*QSTR + CDIM + 16];
    ka3 = *(const short8v*)&kvbase[(size_t)t2*QSTR + CDIM + 24];
  }
  int p = 0;
  for (int s0 = 0; s0 < TDIM; s0 += 128, p ^= 1) {
    if (isV) {
      union { short8v s; unsigned u[4]; } A, C;
      A.s = va0; C.s = vb0;
      #pragma unroll
      for (int j=0;j<4;++j) {
        *(unsigned*)&Vt[p][(dgb*8+2*j  )*VTS + 2*kp] = __builtin_amdgcn_perm(C.u[j], A.u[j], 0x05040100u);
        *(unsigned*)&Vt[p][(dgb*8+2*j+1)*VTS + 2*kp] = __builtin_amdgcn_perm(C.u[j], A.u[j], 0x07060302u);
      }
      A.s = va1; C.s = vb1;
      #pragma unroll
      for (int j=0;j<4;++j) {
        *(unsigned*)&Vt[p][((dgb+2)*8+2*j  )*VTS + 2*kp] = __builtin_amdgcn_perm(C.u[j], A.u[j], 0x05040100u);
        *(unsigned*)&Vt[p][((dgb+2)*8+2*j+1)*VTS + 2*kp] = __builtin_amdgcn_perm(C.u[j], A.u[j], 0x07060302u);
      }
    } else {
      *(short8v*)&Ks[p][t2*KSS +  0] = ka0;
      *(short8v*)&Ks[p][t2*KSS +  8] = ka1;
      *(short8v*)&Ks[p][t2*KSS + 16] = ka2;
      *(short8v*)&Ks[p][t2*KSS + 24] = ka3;
    }
    if (s0 + 128 < TDIM) {
      const short* nb = kvbase + (size_t)(s0+128)*QSTR;
      if (isV) {
        va0 = *(const short8v*)&nb[(size_t)(2*kp)*QSTR   + 2*CDIM + dgb*8];
        vb0 = *(const short8v*)&nb[(size_t)(2*kp+1)*QSTR + 2*CDIM + dgb*8];
        va1 = *(const short8v*)&nb[(size_t)(2*kp)*QSTR   + 2*CDIM + (dgb+2)*8];
        vb1 = *(const short8v*)&nb[(size_t)(2*kp+1)*QSTR + 2*CDIM + (dgb+2)*8];
      } else {
        ka0 = *(const short8v*)&nb[(size_t)t2*QSTR + CDIM +  0];
        ka1 = *(const short8v*)&nb[(size_t)t2*QSTR + CDIM +  8];
        ka2 = *(const short8v*)&nb[(size_t)t2*QSTR + CDIM + 16];
        ka3 = *(const short8v*)&nb[(size_t)t2*QSTR + CDIM + 24];
      }
    }
    __syncthreads();
    #pragma unroll
    for (int ks = 0; ks < 8; ++ks) {
      short8v Kf = *(const short8v*)&Ks[p][(ks*16 + r)*KSS + q4*8];
      float4v sv = mfma32(Kf, Qf, (float4v){0,0,0,0});
      short4v Vf0 = *(const short4v*)&Vt[p][r*VTS + ks*16 + q4*4];
      short4v Vf1 = *(const short4v*)&Vt[p][(16+r)*VTS + ks*16 + q4*4];
      float p0 = fexp2(sv[0]), p1 = fexp2(sv[1]);
      float p2 = fexp2(sv[2]), p3 = fexp2(sv[3]);
      l0 += (p0+p1) + (p2+p3);
      union { unsigned u[2]; short4v s; } P;
      P.u[0] = pkbf(p0, p1); P.u[1] = pkbf(p2, p3);
      o0 = mfma16(P.s, Vf0, o0);
      o1 = mfma16(P.s, Vf1, o1);
    }
    __syncthreads();
  }
  l0 += __shfl_xor(l0, 16, 64); l0 += __shfl_xor(l0, 32, 64);
  #pragma unroll
  for (int reg=0; reg<4; ++reg) {
    int qrow = q4*4 + reg;
    float i0 = 1.f / __shfl(l0, qrow, 64);
    short* op = O + ((size_t)(b*TDIM + rowbase + qrow))*CDIM + h*HSZ;
    op[r]    = f2bs(o0[reg]*i0);
    op[16+r] = f2bs(o1[reg]*i0);
  }
}

// ---------------- fused final-LN + mean-pool ----------------
__global__ __launch_bounds__(256) void k_poolln(const float* __restrict__ X, float* __restrict__ part) {
  __shared__ float red[4][256];
  int b = blockIdx.x >> 3, chunk = blockIdx.x & 7;
  int wv = threadIdx.x >> 6, lane = threadIdx.x & 63;
  int base = b*TDIM + chunk*256 + wv*64;
  float a0=0,a1=0,a2=0,a3=0;
  for (int rr=0; rr<64; ++rr) {
    float4 v = *(const float4*)&X[(size_t)(base+rr)*CDIM + lane*4];
    float s1 = (v.x+v.y)+(v.z+v.w);
    float s2 = fmaf(v.x,v.x, fmaf(v.y,v.y, fmaf(v.z,v.z, v.w*v.w)));
    #pragma unroll
    for (int off=32; off>0; off>>=1) { s1 += __shfl_xor(s1,off,64); s2 += __shfl_xor(s2,off,64); }
    float mean = s1*(1.f/256.f);
    float inv  = rsqrtf(s2*(1.f/256.f) - mean*mean + 1e-5f);
    a0 = fmaf(v.x-mean, inv, a0); a1 = fmaf(v.y-mean, inv, a1);
    a2 = fmaf(v.z-mean, inv, a2); a3 = fmaf(v.w-mean, inv, a3);
  }
  red[wv][lane*4+0]=a0; red[wv][lane*4+1]=a1; red[wv][lane*4+2]=a2; red[wv][lane*4+3]=a3;
  __syncthreads();
  int c = threadIdx.x;
  part[blockIdx.x*256 + c] = (red[0][c]+red[1][c]+red[2][c]+red[3][c]) * (1.f/2048.f);
}

// ---------------- fused classifier ----------------
__global__ __launch_bounds__(512) void k_cls(const float* __restrict__ part,
    const float* __restrict__ Wc1s, const float* __restrict__ bc1f,
    const float* __restrict__ Wc2, const float* __restrict__ bc2, float* __restrict__ out) {
  __shared__ float se[4][256];
  __shared__ float sh[4][512];
  __shared__ float red[160];
  __shared__ float sl[40];
  const int t = threadIdx.x;
  for (int j=t; j<1024; j+=512) {
    int b = j >> 8, c = j & 255;
    float s = 0.f;
    #pragma unroll
    for (int ch=0; ch<8; ++ch) s += part[(b*8+ch)*256 + c];
    se[b][c] = s;
  }
  __syncthreads();
  {
    float bb = bc1f[t];
    float a0=bb, a1=bb, a2=bb, a3=bb;
    for (int c=0; c<256; ++c) {
      float w2 = Wc1s[c*512 + t];
      a0 = fmaf(se[0][c], w2, a0); a1 = fmaf(se[1][c], w2, a1);
      a2 = fmaf(se[2][c], w2, a2); a3 = fmaf(se[3][c], w2, a3);
    }
    sh[0][t]=fmaxf(a0,0.f); sh[1][t]=fmaxf(a1,0.f);
    sh[2][t]=fmaxf(a2,0.f); sh[3][t]=fmaxf(a3,0.f);
  }
  __syncthreads();
  if (t < 160) {
    int o = t >> 2, pp = t & 3;
    int b = o / 10, j = o - b*10;
    const float* hp = &sh[b][pp*128];
    float s = 0.f;
    #pragma unroll 8
    for (int u=0; u<128; ++u) s = fmaf(hp[u], Wc2[(pp*128+u)*10 + j], s);
    red[t] = s;
  }
  __syncthreads();
  if (t < 40) sl[t] = (red[t*4]+red[t*4+1]) + (red[t*4+2]+red[t*4+3]) + bc2[t%10];
  __syncthreads();
  if (t < 4) {
    float mx = -1e30f;
    for (int j=0;j<10;++j) mx = fmaxf(mx, sl[t*10+j]);
    float e[10], sum = 0.f;
    for (int j=0;j<10;++j) { e[j] = __expf(sl[t*10+j]-mx); sum += e[j]; }
    float inv = 1.f/sum;
    for (int j=0;j<10;++j) out[t*10+j] = e[j]*inv;
  }
}

extern "C" void kernel_launch(void* const* d_in, const int* in_sizes, int n_in,
                              void* d_out, int out_size, void* d_ws, size_t ws_size,
                              hipStream_t stream) {
  const int*   idx = (const int*)d_in[0];
  const float* tok = (const float*)d_in[1];
  const float* pos = (const float*)d_in[2];
  const float* Wq  = (const float*)d_in[3];
  const float* Wk  = (const float*)d_in[4];
  const float* Wv  = (const float*)d_in[5];
  const float* Wp  = (const float*)d_in[6];
  const float* bp  = (const float*)d_in[7];
  const float* l1g = (const float*)d_in[8];
  const float* l1b = (const float*)d_in[9];
  const float* l2g = (const float*)d_in[10];
  const float* l2b = (const float*)d_in[11];
  const float* W1  = (const float*)d_in[12];
  const float* b1  = (const float*)d_in[13];
  const float* W2  = (const float*)d_in[14];
  const float* b2  = (const float*)d_in[15];
  const float* lfg = (const float*)d_in[16];
  const float* lfb = (const float*)d_in[17];
  const float* Wc1 = (const float*)d_in[18];
  const float* bc1 = (const float*)d_in[19];
  const float* Wc2 = (const float*)d_in[20];
  const float* bc2 = (const float*)d_in[21];

  char* p = (char*)d_ws;
  float* xb   = (float*)p;              p += (size_t)BUF*4;
  short* hb   = (short*)p;              p += (size_t)BUF*2;
  short* qkvb = (short*)p;              p += (size_t)NTOK*QSTR*2;
  float* part = (float*)p;              p += 32*256*4;
  short* wqkvT = (short*)p;             p += (size_t)LNUM*QSTR*256*2;
  short* wpT   = (short*)p;             p += (size_t)LNUM*65536*2;
  short* w1T   = (short*)p;             p += (size_t)LNUM*65536*2;
  short* w2T   = (short*)p;             p += (size_t)LNUM*65536*2;
  float* bq    = (float*)p;             p += (size_t)LNUM*768*4;
  float* b1f   = (float*)p;             p += (size_t)LNUM*256*4;
  float* Wc1s  = (float*)p;             p += (size_t)256*512*4;
  float* bc1f  = (float*)p;             p += 512*4;

  k_prep_embed<<<513 + NTOK/4, 256, 0, stream>>>(idx, tok, pos,
                                   Wq, Wk, Wv, Wp, W1, W2, l1g, l2g, l1b, l2b,
                                   b1, Wc1, lfg, lfb, bc1,
                                   wqkvT, wpT, w1T, w2T, bq, b1f, Wc1s, bc1f,
                                   xb, hb);
  k_gemm3<4,true,false,true,false><<<dim3(256,12), 64, 0, stream>>>(
      hb, wqkvT, bq, qkvb, QSTR);
  for (int l = 0; l < LNUM; ++l) {
    k_attn6<<<dim3(32, HDIM, BDIM), 256, 0, stream>>>(qkvb, hb);
    if (l < LNUM-1) {
      k_mlp<false><<<256, 1024, 0, stream>>>(
          hb, wpT + (size_t)l*65536, bp + l*CDIM,
          w1T + (size_t)l*65536, b1f + l*CDIM, w2T + (size_t)l*65536, b2 + l*CDIM,
          xb,
          wqkvT + (size_t)(l+1)*QSTR*256, bq + (l+1)*768, qkvb);
    } else {
      k_mlp<true><<<256, 1024, 0, stream>>>(
          hb, wpT + (size_t)l*65536, bp + l*CDIM,
          w1T + (size_t)l*65536, b1f + l*CDIM, w2T + (size_t)l*65536, b2 + l*CDIM,
          xb,
          wqkvT, bq, qkvb);
    }
  }
  k_poolln<<<32, 256, 0, stream>>>(xb, part);
  k_cls<<<1, 512, 0, stream>>>(part, Wc1s, bc1f, Wc2, bc2, (float*)d_out);
}

// Round 11
// 473.730 us; speedup vs baseline: 1.0747x; 1.0747x over previous
//
#include <hip/hip_runtime.h>
#include <hip/hip_bf16.h>

#define NTOK 8192      // B*T
#define CDIM 256
#define TDIM 2048
#define BDIM 4
#define HDIM 8
#define HSZ  32
#define LNUM 4
#define BUF  (NTOK*CDIM)
#define QSTR 768       // fused qkv row stride
#define LC   0.0901684400056f   // 2^-4 * log2(e), folded into Wq/bq

typedef __attribute__((ext_vector_type(8))) short short8v;
typedef __attribute__((ext_vector_type(4))) short short4v;
typedef __attribute__((ext_vector_type(4))) float float4v;

// ---- fp32 -> bf16 pack helpers ----
#if __has_builtin(__builtin_amdgcn_cvt_pk_bf16_f32)
static __device__ __forceinline__ unsigned pkbf(float a, float b){
  auto t = __builtin_amdgcn_cvt_pk_bf16_f32(a, b);
  union { decltype(t) v; unsigned u; } cv; cv.v = t;
  return cv.u;
}
static __device__ __forceinline__ short f2bs(float f){
  auto t = __builtin_amdgcn_cvt_pk_bf16_f32(f, f);
  union { decltype(t) v; unsigned u; } cv; cv.v = t;
  return (short)(cv.u & 0xFFFFu);
}
#else
static __device__ __forceinline__ short f2bs(float f){
  union { float f; unsigned u; } x; x.f = f;
  unsigned r = x.u + 0x7FFFu + ((x.u >> 16) & 1u);
  return (short)(r >> 16);
}
static __device__ __forceinline__ unsigned pkbf(float a, float b){
  union { float f; unsigned u; } x, y; x.f = a; y.f = b;
  unsigned ra = x.u + 0x7FFFu + ((x.u >> 16) & 1u);
  unsigned rb = y.u + 0x7FFFu + ((y.u >> 16) & 1u);
  return __builtin_amdgcn_perm(rb, ra, 0x07060302u);
}
#endif
#if __has_builtin(__builtin_amdgcn_exp2f)
static __device__ __forceinline__ float fexp2(float x){ return __builtin_amdgcn_exp2f(x); }
#else
static __device__ __forceinline__ float fexp2(float x){ return __expf(x*0.6931471805599453f); }
#endif

#if __has_builtin(__builtin_amdgcn_mfma_f32_16x16x16bf16_1k)
static __device__ __forceinline__ float4v mfma16(short4v a, short4v b, float4v c){
  return __builtin_amdgcn_mfma_f32_16x16x16bf16_1k(a, b, c, 0, 0, 0);
}
#else
static __device__ __forceinline__ float4v mfma16(short4v a, short4v b, float4v c){
  float4v d;
  asm volatile("v_mfma_f32_16x16x16_bf16 %0, %1, %2, %3\n\ts_nop 7\n\ts_nop 7"
               : "=v"(d) : "v"(a), "v"(b), "v"(c));
  return d;
}
#endif
static __device__ __forceinline__ float4v mfma32(short8v a, short8v b, float4v c){
  return __builtin_amdgcn_mfma_f32_16x16x32_bf16(a, b, c, 0, 0, 0);
}

// fragment-packed weight address: value (n,k) -> cg=n>>4, ks=k>>5, lane=((k>>3)&3)*16+(n&15), j=k&7
static __device__ __forceinline__ int faddr(int n, int k){
  return ((n>>4)*8 + (k>>5))*512 + ((((k>>3)&3)<<4) + (n&15))*8 + (k&7);
}

// ---------------- merged weight prep + bias folding + embedding + LN1(layer0) ----------------
__global__ __launch_bounds__(256) void k_prep_embed(
    const int* __restrict__ idx, const float* __restrict__ tok, const float* __restrict__ pos,
    const float* __restrict__ Wq, const float* __restrict__ Wk, const float* __restrict__ Wv,
    const float* __restrict__ Wp, const float* __restrict__ W1, const float* __restrict__ W2,
    const float* __restrict__ l1g, const float* __restrict__ l2g,
    const float* __restrict__ l1b, const float* __restrict__ l2b,
    const float* __restrict__ b1, const float* __restrict__ Wc1, const float* __restrict__ lnfg,
    const float* __restrict__ lnfb, const float* __restrict__ bc1,
    short* __restrict__ qkvT, short* __restrict__ wpT, short* __restrict__ w1T, short* __restrict__ w2T,
    float* __restrict__ bq, float* __restrict__ b1f, float* __restrict__ Wc1s, float* __restrict__ bc1f,
    float* __restrict__ x, short* __restrict__ y) {
  const int tid = threadIdx.x;
  const int id = blockIdx.x;
  if (id >= 513) {
    // ---- embedding + LN path ----
    const int bid = id - 513;
    const int lane = tid & 63;
    const int bt = bid*4 + (tid >> 6);
    const int t = bt & (TDIM-1);
    float4 tv = *(const float4*)&tok[(size_t)idx[bt]*CDIM + lane*4];
    float4 pv = *(const float4*)&pos[(size_t)t*CDIM + lane*4];
    float4 v = make_float4(tv.x+pv.x, tv.y+pv.y, tv.z+pv.z, tv.w+pv.w);
    *(float4*)&x[(size_t)bt*CDIM + lane*4] = v;
    float s1 = (v.x+v.y) + (v.z+v.w);
    float s2 = fmaf(v.x,v.x, fmaf(v.y,v.y, fmaf(v.z,v.z, v.w*v.w)));
    #pragma unroll
    for (int off=32; off>0; off>>=1) { s1 += __shfl_xor(s1, off, 64); s2 += __shfl_xor(s2, off, 64); }
    float mean = s1*(1.f/CDIM);
    float inv  = rsqrtf(s2*(1.f/CDIM) - mean*mean + 1e-5f);
    float cc = -mean*inv;
    union { unsigned u[2]; short4v s; } o;
    o.u[0] = pkbf(fmaf(v.x,inv,cc), fmaf(v.y,inv,cc));
    o.u[1] = pkbf(fmaf(v.z,inv,cc), fmaf(v.w,inv,cc));
    *(short4v*)&y[(size_t)bt*CDIM + lane*4] = o.s;
    return;
  }
  if (id < 384) {
    __shared__ float tile[64][65];
    int l = id / 96, rr = id % 96;
    const float* src; short* dst; int n0, k0; bool qkvmode; int gsel; float nscale = 1.f;
    if (rr < 48) {
      int tn = rr >> 2, tk = rr & 3;
      n0 = tn*64; k0 = tk*64;
      const float* b3 = (n0 < 256) ? Wq : (n0 < 512 ? Wk : Wv);
      src = b3 + l*65536;
      dst = qkvT + (size_t)l*QSTR*256;
      qkvmode = true; gsel = 1;
      if (n0 < 256) nscale = LC;
    } else {
      int r2 = rr - 48;
      int mat = r2 >> 4, t = r2 & 15;
      int tn = t >> 2, tk = t & 3;
      n0 = tn*64; k0 = tk*64;
      const float* b3 = (mat == 0) ? Wp : (mat == 1 ? W1 : W2);
      src = b3 + l*65536;
      dst = (mat == 0 ? wpT : (mat == 1 ? w1T : w2T)) + l*65536;
      qkvmode = false; gsel = (mat == 1) ? 2 : 0;
    }
    const int cn = tid & 63, rk = tid >> 6;
    #pragma unroll
    for (int i = 0; i < 16; ++i) {
      int kk = rk + i*4;
      int n = n0 + cn, k = k0 + kk;
      float v;
      if (qkvmode) { int nn = n & 255; v = src[((nn>>5)*256 + k)*32 + (nn & 31)]; }
      else         { v = src[k*256 + n]; }
      if (gsel == 1)      v *= l1g[l*256 + k];
      else if (gsel == 2) v *= l2g[l*256 + k];
      tile[kk][cn] = v;
    }
    __syncthreads();
    #pragma unroll
    for (int i = 0; i < 16; ++i) {
      int nn = rk + i*4;
      dst[faddr(n0 + nn, k0 + cn)] = f2bs(tile[cn][nn] * nscale);
    }
  } else if (id < 448) {
    __shared__ float red[4][64];
    int bid = id - 384;
    int l = bid >> 4, seg = bid & 15;
    int o = seg*64 + (tid & 63), pp = tid >> 6;
    float s = 0.f;
    if (o < 768) {
      const float* W = (o < 256 ? Wq : (o < 512 ? Wk : Wv)) + l*65536;
      int nn = o & 255, h = nn >> 5, d = nn & 31;
      const float* bv = l1b + l*256;
      for (int k = pp*64; k < pp*64+64; ++k) s = fmaf(bv[k], W[(h*256 + k)*32 + d], s);
    } else {
      const float* W = W1 + l*65536;
      int n = o - 768;
      const float* bv = l2b + l*256;
      for (int k = pp*64; k < pp*64+64; ++k) s = fmaf(bv[k], W[k*256 + n], s);
    }
    red[pp][tid & 63] = s;
    __syncthreads();
    if (tid < 64) {
      float tot = red[0][tid]+red[1][tid]+red[2][tid]+red[3][tid];
      int oo = seg*64 + tid;
      if (oo < 768) bq[l*768 + oo] = tot * (oo < 256 ? LC : 1.f);
      else          b1f[l*256 + (oo-768)] = b1[l*256 + (oo-768)] + tot;
    }
  } else if (id < 512) {
    int base = (id-448)*2048;
    #pragma unroll
    for (int i=0;i<8;++i) {
      int idx2 = base + i*256 + tid;
      Wc1s[idx2] = Wc1[idx2] * lnfg[idx2 >> 9];
    }
  } else {
    for (int u = tid; u < 512; u += 256) {
      float s = bc1[u];
      for (int k=0;k<256;++k) s = fmaf(lnfb[k], Wc1[k*512+u], s);
      bc1f[u] = s;
    }
  }
}

// ---------------- LDS-free MFMA GEMM (QKV layer 0): C = A(bf16) x Bfrag(packed) ----------------
template<int NF, bool BIAS, bool RELU, bool OUTBF16, bool ACCUM>
__global__ __launch_bounds__(64) void k_gemm3(const short* __restrict__ A,
    const short* __restrict__ Bt, const float* __restrict__ bias, void* __restrict__ Cv,
    int outstride) {
  const int lane = threadIdx.x;
  const int q4 = lane >> 4, r = lane & 15;
  const int blockRow = blockIdx.x * 32;
  const int blockCol = blockIdx.y * (NF*16);
  float4v acc[2][NF];
  #pragma unroll
  for (int i=0;i<2;++i)
    #pragma unroll
    for (int j=0;j<NF;++j) acc[i][j] = (float4v){0,0,0,0};
  #pragma unroll
  for (int k0 = 0; k0 < 256; k0 += 32) {
    short8v a0 = *(const short8v*)&A[(size_t)(blockRow +      r)*CDIM + k0 + q4*8];
    short8v a1 = *(const short8v*)&A[(size_t)(blockRow + 16 + r)*CDIM + k0 + q4*8];
    #pragma unroll
    for (int nf=0; nf<NF; ++nf) {
      short8v bf = *(const short8v*)&Bt[(size_t)(((blockCol>>4) + nf)*8 + (k0>>5))*512 + lane*8];
      acc[0][nf] = mfma32(a0, bf, acc[0][nf]);
      acc[1][nf] = mfma32(a1, bf, acc[1][nf]);
    }
  }
  #pragma unroll
  for (int mf=0; mf<2; ++mf)
    #pragma unroll
    for (int nf=0; nf<NF; ++nf) {
      int col = blockCol + nf*16 + r;
      float bb = BIAS ? bias[col] : 0.f;
      #pragma unroll
      for (int reg=0; reg<4; ++reg) {
        int row = blockRow + mf*16 + q4*4 + reg;
        float v = acc[mf][nf][reg] + bb;
        if (RELU) v = fmaxf(v, 0.f);
        size_t oi = (size_t)row*outstride + col;
        if (ACCUM)        ((float*)Cv)[oi] += v;
        else if (OUTBF16) ((short*)Cv)[oi] = f2bs(v);
        else              ((float*)Cv)[oi] = v;
      }
    }
}

// ---------------- fused per-layer MLP: proj+res+LN1 -> FFN -> res+LN2 -> next-layer QKV ------
template<bool LAST>
__global__ __launch_bounds__(1024, 4) void k_mlp(
    const short* __restrict__ A,            // attn output rows (bf16, stride CDIM)
    const short* __restrict__ Bt,           // wpT layer l (fragment-packed)
    const float* __restrict__ bias,         // bproj layer l
    const short* __restrict__ W1t, const float* __restrict__ b1f,
    const short* __restrict__ W2t, const float* __restrict__ b2,
    float* __restrict__ X,                  // fp32 residual stream
    const short* __restrict__ Wqkv,         // qkvT layer l+1 (fragment-packed; unused if LAST)
    const float* __restrict__ bq,           // bq layer l+1   (unused if LAST)
    short* __restrict__ Qout) {             // qkvb           (unused if LAST)
  __shared__ __align__(16) short Ys[32*264];
  __shared__ __align__(16) short Gs[32*264];
  __shared__ float S1[32][16], S2[32][16];
  const int tid = threadIdx.x;
  const int w = tid >> 6, lane = tid & 63;
  const int q4 = lane >> 4, r = lane & 15;
  const int row0 = blockIdx.x * 32;
  const int colw = w*16 + r;               // this wave's output column, phases A/B

  // ===== stage A tile (32x256 bf16 = 16KB) into Gs, fully coalesced =====
  {
    short8v av = *(const short8v*)&A[(size_t)row0*CDIM + tid*8];
    *(short8v*)&Gs[(tid>>5)*264 + (tid&31)*8] = av;
  }
  __syncthreads();

  // ===== Phase A: proj GEMM (A from LDS, B packed) =====
  float4v acc0 = {0,0,0,0}, acc1 = {0,0,0,0};
  #pragma unroll
  for (int k=0;k<8;++k) {
    short8v b  = *(const short8v*)&Bt[(size_t)(w*8+k)*512 + lane*8];
    short8v a0 = *(const short8v*)&Gs[(     r)*264 + k*32 + q4*8];
    short8v a1 = *(const short8v*)&Gs[(16 + r)*264 + k*32 + q4*8];
    acc0 = mfma32(a0, b, acc0);
    acc1 = mfma32(a1, b, acc1);
  }
  float xv0[4], xv1[4];
  {
    float bb = bias[colw];
    #pragma unroll
    for (int reg=0; reg<4; ++reg) {
      float t0 = acc0[reg] + bb + X[(size_t)(row0 +      q4*4 + reg)*CDIM + colw];
      float t1 = acc1[reg] + bb + X[(size_t)(row0 + 16 + q4*4 + reg)*CDIM + colw];
      xv0[reg] = t0; xv1[reg] = t1;
      float s10 = t0, s20 = t0*t0, s11 = t1, s21 = t1*t1;
      #pragma unroll
      for (int off=1; off<16; off<<=1) {
        s10 += __shfl_xor(s10, off, 64); s20 += __shfl_xor(s20, off, 64);
        s11 += __shfl_xor(s11, off, 64); s21 += __shfl_xor(s21, off, 64);
      }
      if (r == 0) {
        S1[     q4*4 + reg][w] = s10; S2[     q4*4 + reg][w] = s20;
        S1[16 + q4*4 + reg][w] = s11; S2[16 + q4*4 + reg][w] = s21;
      }
    }
  }
  __syncthreads();
  // LN1 -> Ys
  #pragma unroll
  for (int reg=0; reg<4; ++reg) {
    int r0i = q4*4 + reg, r1i = 16 + q4*4 + reg;
    float s1=0.f, s2=0.f, t1=0.f, t2=0.f;
    #pragma unroll
    for (int j=0;j<16;++j) { s1 += S1[r0i][j]; s2 += S2[r0i][j]; t1 += S1[r1i][j]; t2 += S2[r1i][j]; }
    float mean = s1*(1.f/CDIM);
    float inv  = rsqrtf(s2*(1.f/CDIM) - mean*mean + 1e-5f);
    Ys[r0i*264 + colw] = f2bs(fmaf(xv0[reg], inv, -mean*inv));
    float mean2 = t1*(1.f/CDIM);
    float inv2  = rsqrtf(t2*(1.f/CDIM) - mean2*mean2 + 1e-5f);
    Ys[r1i*264 + colw] = f2bs(fmaf(xv1[reg], inv2, -mean2*inv2));
  }
  __syncthreads();

  // ===== FFN1: A from Ys, B packed -> relu -> Gs =====
  acc0 = (float4v){0,0,0,0}; acc1 = (float4v){0,0,0,0};
  #pragma unroll
  for (int k=0;k<8;++k) {
    short8v b  = *(const short8v*)&W1t[(size_t)(w*8+k)*512 + lane*8];
    short8v a0 = *(const short8v*)&Ys[(     r)*264 + k*32 + q4*8];
    short8v a1 = *(const short8v*)&Ys[(16 + r)*264 + k*32 + q4*8];
    acc0 = mfma32(a0, b, acc0);
    acc1 = mfma32(a1, b, acc1);
  }
  {
    float g = b1f[colw];
    #pragma unroll
    for (int reg=0; reg<4; ++reg) {
      Gs[(     q4*4 + reg)*264 + colw] = f2bs(fmaxf(acc0[reg] + g, 0.f));
      Gs[(16 + q4*4 + reg)*264 + colw] = f2bs(fmaxf(acc1[reg] + g, 0.f));
    }
  }
  __syncthreads();

  // ===== FFN2: A from Gs, B packed + residual [+ LN2 -> Ys] =====
  acc0 = (float4v){0,0,0,0}; acc1 = (float4v){0,0,0,0};
  #pragma unroll
  for (int k=0;k<8;++k) {
    short8v b  = *(const short8v*)&W2t[(size_t)(w*8+k)*512 + lane*8];
    short8v a0 = *(const short8v*)&Gs[(     r)*264 + k*32 + q4*8];
    short8v a1 = *(const short8v*)&Gs[(16 + r)*264 + k*32 + q4*8];
    acc0 = mfma32(a0, b, acc0);
    acc1 = mfma32(a1, b, acc1);
  }
  {
    float bb2 = b2[colw];
    #pragma unroll
    for (int reg=0; reg<4; ++reg) {
      float t0 = acc0[reg] + bb2 + xv0[reg];
      float t1 = acc1[reg] + bb2 + xv1[reg];
      xv0[reg] = t0; xv1[reg] = t1;
      X[(size_t)(row0 +      q4*4 + reg)*CDIM + colw] = t0;
      X[(size_t)(row0 + 16 + q4*4 + reg)*CDIM + colw] = t1;
      if (!LAST) {
        float s10 = t0, s20 = t0*t0, s11 = t1, s21 = t1*t1;
        #pragma unroll
        for (int off=1; off<16; off<<=1) {
          s10 += __shfl_xor(s10, off, 64); s20 += __shfl_xor(s20, off, 64);
          s11 += __shfl_xor(s11, off, 64); s21 += __shfl_xor(s21, off, 64);
        }
        if (r == 0) {
          S1[     q4*4 + reg][w] = s10; S2[     q4*4 + reg][w] = s20;
          S1[16 + q4*4 + reg][w] = s11; S2[16 + q4*4 + reg][w] = s21;
        }
      }
    }
  }
  if (LAST) return;
  __syncthreads();
  // LN2 -> Ys
  #pragma unroll
  for (int reg=0; reg<4; ++reg) {
    int r0i = q4*4 + reg, r1i = 16 + q4*4 + reg;
    float s1=0.f, s2=0.f, t1=0.f, t2=0.f;
    #pragma unroll
    for (int j=0;j<16;++j) { s1 += S1[r0i][j]; s2 += S2[r0i][j]; t1 += S1[r1i][j]; t2 += S2[r1i][j]; }
    float mean = s1*(1.f/CDIM);
    float inv  = rsqrtf(s2*(1.f/CDIM) - mean*mean + 1e-5f);
    Ys[r0i*264 + colw] = f2bs(fmaf(xv0[reg], inv, -mean*inv));
    float mean2 = t1*(1.f/CDIM);
    float inv2  = rsqrtf(t2*(1.f/CDIM) - mean2*mean2 + 1e-5f);
    Ys[r1i*264 + colw] = f2bs(fmaf(xv1[reg], inv2, -mean2*inv2));
  }
  __syncthreads();

  // ===== Phase C: next-layer QKV GEMM (A from Ys, B packed), wave = 32 rows x 48 cols =====
  {
    float4v qa0[3], qa1[3];
    #pragma unroll
    for (int j=0;j<3;++j) { qa0[j] = (float4v){0,0,0,0}; qa1[j] = (float4v){0,0,0,0}; }
    #pragma unroll
    for (int k=0;k<8;++k) {
      short8v ay0 = *(const short8v*)&Ys[(     r)*264 + k*32 + q4*8];
      short8v ay1 = *(const short8v*)&Ys[(16 + r)*264 + k*32 + q4*8];
      #pragma unroll
      for (int nf=0; nf<3; ++nf) {
        short8v b = *(const short8v*)&Wqkv[(size_t)((w*3+nf)*8 + k)*512 + lane*8];
        qa0[nf] = mfma32(ay0, b, qa0[nf]);
        qa1[nf] = mfma32(ay1, b, qa1[nf]);
      }
    }
    #pragma unroll
    for (int nf=0; nf<3; ++nf) {
      int col = (w*3+nf)*16 + r;
      float bb = bq[col];
      #pragma unroll
      for (int reg=0; reg<4; ++reg) {
        Qout[(size_t)(row0 +      q4*4 + reg)*QSTR + col] = f2bs(qa0[nf][reg] + bb);
        Qout[(size_t)(row0 + 16 + q4*4 + reg)*QSTR + col] = f2bs(qa1[nf][reg] + bb);
      }
    }
  }
}

// ---------------- MFMA flash attention: KV-split (2 halves x 1024 keys), 128 q-rows, dbuf ----
// Linear softmax (no running max): partials combine additively across KV halves.
#define KSS 40
#define VTS 140
__global__ __launch_bounds__(512) void k_attn6(const short* __restrict__ qkv,
    float* __restrict__ opart, float* __restrict__ lpart) {
  __shared__ __align__(16) short Ks[2][128*KSS];
  __shared__ __align__(16) short Vt[2][32*VTS];
  const int tid = threadIdx.x;
  const int w = tid >> 6, lane = tid & 63;
  const int q4 = lane >> 4, r = lane & 15;
  const int b = blockIdx.z & 3, half = blockIdx.z >> 2, h = blockIdx.y;
  const int kv0 = half*1024;
  const int rowbase = blockIdx.x*128 + w*16;
  short8v Qf = *(const short8v*)&qkv[((size_t)(b*TDIM + rowbase + r))*QSTR + h*HSZ + q4*8];
  float4v o0 = {0,0,0,0}, o1 = {0,0,0,0};
  float l0 = 0.f;
  const bool isV = tid >= 256;
  const int t2 = tid & 255;
  const int kkey = t2 >> 1, kd0 = (t2 & 1)*16;
  const int kp = t2 & 63, dg = t2 >> 6;
  const short* kvbase = qkv + (size_t)b*TDIM*QSTR + h*HSZ;
  short8v ka, kb2, va, vb;
  if (isV) {
    va = *(const short8v*)&kvbase[(size_t)(kv0 + 2*kp)*QSTR   + 2*CDIM + dg*8];
    vb = *(const short8v*)&kvbase[(size_t)(kv0 + 2*kp+1)*QSTR + 2*CDIM + dg*8];
  } else {
    ka  = *(const short8v*)&kvbase[(size_t)(kv0 + kkey)*QSTR + CDIM + kd0];
    kb2 = *(const short8v*)&kvbase[(size_t)(kv0 + kkey)*QSTR + CDIM + kd0 + 8];
  }
  int p = 0;
  for (int s0 = 0; s0 < 1024; s0 += 128, p ^= 1) {
    if (isV) {
      union { short8v s; unsigned u[4]; } A, C;
      A.s = va; C.s = vb;
      #pragma unroll
      for (int j=0;j<4;++j) {
        *(unsigned*)&Vt[p][(dg*8+2*j  )*VTS + 2*kp] = __builtin_amdgcn_perm(C.u[j], A.u[j], 0x05040100u);
        *(unsigned*)&Vt[p][(dg*8+2*j+1)*VTS + 2*kp] = __builtin_amdgcn_perm(C.u[j], A.u[j], 0x07060302u);
      }
    } else {
      *(short8v*)&Ks[p][kkey*KSS + kd0]     = ka;
      *(short8v*)&Ks[p][kkey*KSS + kd0 + 8] = kb2;
    }
    if (s0 + 128 < 1024) {
      const short* nb = kvbase + (size_t)(kv0 + s0 + 128)*QSTR;
      if (isV) {
        va = *(const short8v*)&nb[(size_t)(2*kp)*QSTR   + 2*CDIM + dg*8];
        vb = *(const short8v*)&nb[(size_t)(2*kp+1)*QSTR + 2*CDIM + dg*8];
      } else {
        ka  = *(const short8v*)&nb[(size_t)kkey*QSTR + CDIM + kd0];
        kb2 = *(const short8v*)&nb[(size_t)kkey*QSTR + CDIM + kd0 + 8];
      }
    }
    __syncthreads();
    #pragma unroll
    for (int ks = 0; ks < 8; ++ks) {
      short8v Kf = *(const short8v*)&Ks[p][(ks*16 + r)*KSS + q4*8];
      float4v sv = mfma32(Kf, Qf, (float4v){0,0,0,0});
      short4v Vf0 = *(const short4v*)&Vt[p][r*VTS + ks*16 + q4*4];
      short4v Vf1 = *(const short4v*)&Vt[p][(16+r)*VTS + ks*16 + q4*4];
      float p0 = fexp2(sv[0]), p1 = fexp2(sv[1]);
      float p2 = fexp2(sv[2]), p3 = fexp2(sv[3]);
      l0 += (p0+p1) + (p2+p3);
      union { unsigned u[2]; short4v s; } P;
      P.u[0] = pkbf(p0, p1); P.u[1] = pkbf(p2, p3);
      o0 = mfma16(P.s, Vf0, o0);
      o1 = mfma16(P.s, Vf1, o1);
    }
  }
  l0 += __shfl_xor(l0, 16, 64); l0 += __shfl_xor(l0, 32, 64);
  if (lane < 16)
    lpart[(size_t)half*NTOK*HDIM + (size_t)(b*TDIM + rowbase + lane)*HDIM + h] = l0;
  #pragma unroll
  for (int reg=0; reg<4; ++reg) {
    int qrow = q4*4 + reg;
    float* op = opart + (size_t)half*BUF + ((size_t)(b*TDIM + rowbase + qrow))*CDIM + h*HSZ;
    op[r]    = o0[reg];
    op[16+r] = o1[reg];
  }
}

// ---------------- combine KV-split partials: O = (o1+o2)/(l1+l2), bf16 out ----------------
__global__ __launch_bounds__(256) void k_attncomb(const float* __restrict__ opart,
    const float* __restrict__ lpart, short* __restrict__ O) {
  int f = blockIdx.x*256 + threadIdx.x;     // float4 index; total NTOK*CDIM/4
  int bt = f >> 6;
  int c4 = (f & 63)*4;
  int h = c4 >> 5;
  float l = lpart[(size_t)bt*HDIM + h] + lpart[(size_t)NTOK*HDIM + (size_t)bt*HDIM + h];
  float inv = 1.f / l;
  float4 a = *(const float4*)&opart[(size_t)bt*CDIM + c4];
  float4 bv = *(const float4*)&opart[(size_t)BUF + (size_t)bt*CDIM + c4];
  union { unsigned u[2]; short4v s; } o;
  o.u[0] = pkbf((a.x+bv.x)*inv, (a.y+bv.y)*inv);
  o.u[1] = pkbf((a.z+bv.z)*inv, (a.w+bv.w)*inv);
  *(short4v*)&O[(size_t)bt*CDIM + c4] = o.s;
}

// ---------------- fused final-LN + mean-pool ----------------
__global__ __launch_bounds__(256) void k_poolln(const float* __restrict__ X, float* __restrict__ part) {
  __shared__ float red[4][256];
  int b = blockIdx.x >> 3, chunk = blockIdx.x & 7;
  int wv = threadIdx.x >> 6, lane = threadIdx.x & 63;
  int base = b*TDIM + chunk*256 + wv*64;
  float a0=0,a1=0,a2=0,a3=0;
  for (int rr=0; rr<64; ++rr) {
    float4 v = *(const float4*)&X[(size_t)(base+rr)*CDIM + lane*4];
    float s1 = (v.x+v.y)+(v.z+v.w);
    float s2 = fmaf(v.x,v.x, fmaf(v.y,v.y, fmaf(v.z,v.z, v.w*v.w)));
    #pragma unroll
    for (int off=32; off>0; off>>=1) { s1 += __shfl_xor(s1,off,64); s2 += __shfl_xor(s2,off,64); }
    float mean = s1*(1.f/256.f);
    float inv  = rsqrtf(s2*(1.f/256.f) - mean*mean + 1e-5f);
    a0 = fmaf(v.x-mean, inv, a0); a1 = fmaf(v.y-mean, inv, a1);
    a2 = fmaf(v.z-mean, inv, a2); a3 = fmaf(v.w-mean, inv, a3);
  }
  red[wv][lane*4+0]=a0; red[wv][lane*4+1]=a1; red[wv][lane*4+2]=a2; red[wv][lane*4+3]=a3;
  __syncthreads();
  int c = threadIdx.x;
  part[blockIdx.x*256 + c] = (red[0][c]+red[1][c]+red[2][c]+red[3][c]) * (1.f/2048.f);
}

// ---------------- fused classifier ----------------
__global__ __launch_bounds__(512) void k_cls(const float* __restrict__ part,
    const float* __restrict__ Wc1s, const float* __restrict__ bc1f,
    const float* __restrict__ Wc2, const float* __restrict__ bc2, float* __restrict__ out) {
  __shared__ float se[4][256];
  __shared__ float sh[4][512];
  __shared__ float red[160];
  __shared__ float sl[40];
  const int t = threadIdx.x;
  for (int j=t; j<1024; j+=512) {
    int b = j >> 8, c = j & 255;
    float s = 0.f;
    #pragma unroll
    for (int ch=0; ch<8; ++ch) s += part[(b*8+ch)*256 + c];
    se[b][c] = s;
  }
  __syncthreads();
  {
    float bb = bc1f[t];
    float a0=bb, a1=bb, a2=bb, a3=bb;
    for (int c=0; c<256; ++c) {
      float w2 = Wc1s[c*512 + t];
      a0 = fmaf(se[0][c], w2, a0); a1 = fmaf(se[1][c], w2, a1);
      a2 = fmaf(se[2][c], w2, a2); a3 = fmaf(se[3][c], w2, a3);
    }
    sh[0][t]=fmaxf(a0,0.f); sh[1][t]=fmaxf(a1,0.f);
    sh[2][t]=fmaxf(a2,0.f); sh[3][t]=fmaxf(a3,0.f);
  }
  __syncthreads();
  if (t < 160) {
    int o = t >> 2, pp = t & 3;
    int b = o / 10, j = o - b*10;
    const float* hp = &sh[b][pp*128];
    float s = 0.f;
    #pragma unroll 8
    for (int u=0; u<128; ++u) s = fmaf(hp[u], Wc2[(pp*128+u)*10 + j], s);
    red[t] = s;
  }
  __syncthreads();
  if (t < 40) sl[t] = (red[t*4]+red[t*4+1]) + (red[t*4+2]+red[t*4+3]) + bc2[t%10];
  __syncthreads();
  if (t < 4) {
    float mx = -1e30f;
    for (int j=0;j<10;++j) mx = fmaxf(mx, sl[t*10+j]);
    float e[10], sum = 0.f;
    for (int j=0;j<10;++j) { e[j] = __expf(sl[t*10+j]-mx); sum += e[j]; }
    float inv = 1.f/sum;
    for (int j=0;j<10;++j) out[t*10+j] = e[j]*inv;
  }
}

extern "C" void kernel_launch(void* const* d_in, const int* in_sizes, int n_in,
                              void* d_out, int out_size, void* d_ws, size_t ws_size,
                              hipStream_t stream) {
  const int*   idx = (const int*)d_in[0];
  const float* tok = (const float*)d_in[1];
  const float* pos = (const float*)d_in[2];
  const float* Wq  = (const float*)d_in[3];
  const float* Wk  = (const float*)d_in[4];
  const float* Wv  = (const float*)d_in[5];
  const float* Wp  = (const float*)d_in[6];
  const float* bp  = (const float*)d_in[7];
  const float* l1g = (const float*)d_in[8];
  const float* l1b = (const float*)d_in[9];
  const float* l2g = (const float*)d_in[10];
  const float* l2b = (const float*)d_in[11];
  const float* W1  = (const float*)d_in[12];
  const float* b1  = (const float*)d_in[13];
  const float* W2  = (const float*)d_in[14];
  const float* b2  = (const float*)d_in[15];
  const float* lfg = (const float*)d_in[16];
  const float* lfb = (const float*)d_in[17];
  const float* Wc1 = (const float*)d_in[18];
  const float* bc1 = (const float*)d_in[19];
  const float* Wc2 = (const float*)d_in[20];
  const float* bc2 = (const float*)d_in[21];

  char* p = (char*)d_ws;
  float* xb   = (float*)p;              p += (size_t)BUF*4;
  short* hb   = (short*)p;              p += (size_t)BUF*2;
  short* qkvb = (short*)p;              p += (size_t)NTOK*QSTR*2;
  float* part = (float*)p;              p += 32*256*4;
  short* wqkvT = (short*)p;             p += (size_t)LNUM*QSTR*256*2;
  short* wpT   = (short*)p;             p += (size_t)LNUM*65536*2;
  short* w1T   = (short*)p;             p += (size_t)LNUM*65536*2;
  short* w2T   = (short*)p;             p += (size_t)LNUM*65536*2;
  float* bq    = (float*)p;             p += (size_t)LNUM*768*4;
  float* b1f   = (float*)p;             p += (size_t)LNUM*256*4;
  float* Wc1s  = (float*)p;             p += (size_t)256*512*4;
  float* bc1f  = (float*)p;             p += 512*4;
  float* opart = (float*)p;             p += (size_t)2*BUF*4;
  float* lpart = (float*)p;             p += (size_t)2*NTOK*HDIM*4;

  k_prep_embed<<<513 + NTOK/4, 256, 0, stream>>>(idx, tok, pos,
                                   Wq, Wk, Wv, Wp, W1, W2, l1g, l2g, l1b, l2b,
                                   b1, Wc1, lfg, lfb, bc1,
                                   wqkvT, wpT, w1T, w2T, bq, b1f, Wc1s, bc1f,
                                   xb, hb);
  k_gemm3<4,true,false,true,false><<<dim3(256,12), 64, 0, stream>>>(
      hb, wqkvT, bq, qkvb, QSTR);
  for (int l = 0; l < LNUM; ++l) {
    k_attn6<<<dim3(16, HDIM, BDIM*2), 512, 0, stream>>>(qkvb, opart, lpart);
    k_attncomb<<<BUF/1024, 256, 0, stream>>>(opart, lpart, hb);
    if (l < LNUM-1) {
      k_mlp<false><<<256, 1024, 0, stream>>>(
          hb, wpT + (size_t)l*65536, bp + l*CDIM,
          w1T + (size_t)l*65536, b1f + l*CDIM, w2T + (size_t)l*65536, b2 + l*CDIM,
          xb,
          wqkvT + (size_t)(l+1)*QSTR*256, bq + (l+1)*768, qkvb);
    } else {
      k_mlp<true><<<256, 1024, 0, stream>>>(
          hb, wpT + (size_t)l*65536, bp + l*CDIM,
          w1T + (size_t)l*65536, b1f + l*CDIM, w2T + (size_t)l*65536, b2 + l*CDIM,
          xb,
          wqkvT, bq, qkvb);
    }
  }
  k_poolln<<<32, 256, 0, stream>>>(xb, part);
  k_cls<<<1, 512, 0, stream>>>(part, Wc1s, bc1f, Wc2, bc2, (float*)d_out);
}

// Round 12
// 455.502 us; speedup vs baseline: 1.1177x; 1.0400x over previous
//
#include <hip/hip_runtime.h>
#include <hip/hip_bf16.h>

#define NTOK 8192      // B*T
#define CDIM 256
#define TDIM 2048
#define BDIM 4
#define HDIM 8
#define HSZ  32
#define LNUM 4
#define BUF  (NTOK*CDIM)
#define QSTR 768       // fused qkv row stride
#define LC   0.0901684400056f   // 2^-4 * log2(e), folded into Wq/bq

typedef __attribute__((ext_vector_type(8))) short short8v;
typedef __attribute__((ext_vector_type(4))) short short4v;
typedef __attribute__((ext_vector_type(4))) float float4v;

// ---- fp32 -> bf16 pack helpers ----
#if __has_builtin(__builtin_amdgcn_cvt_pk_bf16_f32)
static __device__ __forceinline__ unsigned pkbf(float a, float b){
  auto t = __builtin_amdgcn_cvt_pk_bf16_f32(a, b);
  union { decltype(t) v; unsigned u; } cv; cv.v = t;
  return cv.u;
}
static __device__ __forceinline__ short f2bs(float f){
  auto t = __builtin_amdgcn_cvt_pk_bf16_f32(f, f);
  union { decltype(t) v; unsigned u; } cv; cv.v = t;
  return (short)(cv.u & 0xFFFFu);
}
#else
static __device__ __forceinline__ short f2bs(float f){
  union { float f; unsigned u; } x; x.f = f;
  unsigned r = x.u + 0x7FFFu + ((x.u >> 16) & 1u);
  return (short)(r >> 16);
}
static __device__ __forceinline__ unsigned pkbf(float a, float b){
  union { float f; unsigned u; } x, y; x.f = a; y.f = b;
  unsigned ra = x.u + 0x7FFFu + ((x.u >> 16) & 1u);
  unsigned rb = y.u + 0x7FFFu + ((y.u >> 16) & 1u);
  return __builtin_amdgcn_perm(rb, ra, 0x07060302u);
}
#endif
#if __has_builtin(__builtin_amdgcn_exp2f)
static __device__ __forceinline__ float fexp2(float x){ return __builtin_amdgcn_exp2f(x); }
#else
static __device__ __forceinline__ float fexp2(float x){ return __expf(x*0.6931471805599453f); }
#endif

#if __has_builtin(__builtin_amdgcn_mfma_f32_16x16x16bf16_1k)
static __device__ __forceinline__ float4v mfma16(short4v a, short4v b, float4v c){
  return __builtin_amdgcn_mfma_f32_16x16x16bf16_1k(a, b, c, 0, 0, 0);
}
#else
static __device__ __forceinline__ float4v mfma16(short4v a, short4v b, float4v c){
  float4v d;
  asm volatile("v_mfma_f32_16x16x16_bf16 %0, %1, %2, %3\n\ts_nop 7\n\ts_nop 7"
               : "=v"(d) : "v"(a), "v"(b), "v"(c));
  return d;
}
#endif
static __device__ __forceinline__ float4v mfma32(short8v a, short8v b, float4v c){
  return __builtin_amdgcn_mfma_f32_16x16x32_bf16(a, b, c, 0, 0, 0);
}

// fragment-packed weight address: value (n,k) -> cg=n>>4, ks=k>>5, lane=((k>>3)&3)*16+(n&15), j=k&7
static __device__ __forceinline__ int faddr(int n, int k){
  return ((n>>4)*8 + (k>>5))*512 + ((((k>>3)&3)<<4) + (n&15))*8 + (k&7);
}

// ---------------- merged weight prep + bias folding + embedding + LN1(layer0) ----------------
__global__ __launch_bounds__(256) void k_prep_embed(
    const int* __restrict__ idx, const float* __restrict__ tok, const float* __restrict__ pos,
    const float* __restrict__ Wq, const float* __restrict__ Wk, const float* __restrict__ Wv,
    const float* __restrict__ Wp, const float* __restrict__ W1, const float* __restrict__ W2,
    const float* __restrict__ l1g, const float* __restrict__ l2g,
    const float* __restrict__ l1b, const float* __restrict__ l2b,
    const float* __restrict__ b1, const float* __restrict__ Wc1, const float* __restrict__ lnfg,
    const float* __restrict__ lnfb, const float* __restrict__ bc1,
    short* __restrict__ qkvT, short* __restrict__ wpT, short* __restrict__ w1T, short* __restrict__ w2T,
    float* __restrict__ bq, float* __restrict__ b1f, float* __restrict__ Wc1s, float* __restrict__ bc1f,
    float* __restrict__ x, short* __restrict__ y) {
  const int tid = threadIdx.x;
  const int id = blockIdx.x;
  if (id >= 513) {
    // ---- embedding + LN path ----
    const int bid = id - 513;
    const int lane = tid & 63;
    const int bt = bid*4 + (tid >> 6);
    const int t = bt & (TDIM-1);
    float4 tv = *(const float4*)&tok[(size_t)idx[bt]*CDIM + lane*4];
    float4 pv = *(const float4*)&pos[(size_t)t*CDIM + lane*4];
    float4 v = make_float4(tv.x+pv.x, tv.y+pv.y, tv.z+pv.z, tv.w+pv.w);
    *(float4*)&x[(size_t)bt*CDIM + lane*4] = v;
    float s1 = (v.x+v.y) + (v.z+v.w);
    float s2 = fmaf(v.x,v.x, fmaf(v.y,v.y, fmaf(v.z,v.z, v.w*v.w)));
    #pragma unroll
    for (int off=32; off>0; off>>=1) { s1 += __shfl_xor(s1, off, 64); s2 += __shfl_xor(s2, off, 64); }
    float mean = s1*(1.f/CDIM);
    float inv  = rsqrtf(s2*(1.f/CDIM) - mean*mean + 1e-5f);
    float cc = -mean*inv;
    union { unsigned u[2]; short4v s; } o;
    o.u[0] = pkbf(fmaf(v.x,inv,cc), fmaf(v.y,inv,cc));
    o.u[1] = pkbf(fmaf(v.z,inv,cc), fmaf(v.w,inv,cc));
    *(short4v*)&y[(size_t)bt*CDIM + lane*4] = o.s;
    return;
  }
  if (id < 384) {
    __shared__ float tile[64][65];
    int l = id / 96, rr = id % 96;
    const float* src; short* dst; int n0, k0; bool qkvmode; int gsel; float nscale = 1.f;
    if (rr < 48) {
      int tn = rr >> 2, tk = rr & 3;
      n0 = tn*64; k0 = tk*64;
      const float* b3 = (n0 < 256) ? Wq : (n0 < 512 ? Wk : Wv);
      src = b3 + l*65536;
      dst = qkvT + (size_t)l*QSTR*256;
      qkvmode = true; gsel = 1;
      if (n0 < 256) nscale = LC;
    } else {
      int r2 = rr - 48;
      int mat = r2 >> 4, t = r2 & 15;
      int tn = t >> 2, tk = t & 3;
      n0 = tn*64; k0 = tk*64;
      const float* b3 = (mat == 0) ? Wp : (mat == 1 ? W1 : W2);
      src = b3 + l*65536;
      dst = (mat == 0 ? wpT : (mat == 1 ? w1T : w2T)) + l*65536;
      qkvmode = false; gsel = (mat == 1) ? 2 : 0;
    }
    const int cn = tid & 63, rk = tid >> 6;
    #pragma unroll
    for (int i = 0; i < 16; ++i) {
      int kk = rk + i*4;
      int n = n0 + cn, k = k0 + kk;
      float v;
      if (qkvmode) { int nn = n & 255; v = src[((nn>>5)*256 + k)*32 + (nn & 31)]; }
      else         { v = src[k*256 + n]; }
      if (gsel == 1)      v *= l1g[l*256 + k];
      else if (gsel == 2) v *= l2g[l*256 + k];
      tile[kk][cn] = v;
    }
    __syncthreads();
    #pragma unroll
    for (int i = 0; i < 16; ++i) {
      int nn = rk + i*4;
      dst[faddr(n0 + nn, k0 + cn)] = f2bs(tile[cn][nn] * nscale);
    }
  } else if (id < 448) {
    __shared__ float red[4][64];
    int bid = id - 384;
    int l = bid >> 4, seg = bid & 15;
    int o = seg*64 + (tid & 63), pp = tid >> 6;
    float s = 0.f;
    if (o < 768) {
      const float* W = (o < 256 ? Wq : (o < 512 ? Wk : Wv)) + l*65536;
      int nn = o & 255, h = nn >> 5, d = nn & 31;
      const float* bv = l1b + l*256;
      for (int k = pp*64; k < pp*64+64; ++k) s = fmaf(bv[k], W[(h*256 + k)*32 + d], s);
    } else {
      const float* W = W1 + l*65536;
      int n = o - 768;
      const float* bv = l2b + l*256;
      for (int k = pp*64; k < pp*64+64; ++k) s = fmaf(bv[k], W[k*256 + n], s);
    }
    red[pp][tid & 63] = s;
    __syncthreads();
    if (tid < 64) {
      float tot = red[0][tid]+red[1][tid]+red[2][tid]+red[3][tid];
      int oo = seg*64 + tid;
      if (oo < 768) bq[l*768 + oo] = tot * (oo < 256 ? LC : 1.f);
      else          b1f[l*256 + (oo-768)] = b1[l*256 + (oo-768)] + tot;
    }
  } else if (id < 512) {
    int base = (id-448)*2048;
    #pragma unroll
    for (int i=0;i<8;++i) {
      int idx2 = base + i*256 + tid;
      Wc1s[idx2] = Wc1[idx2] * lnfg[idx2 >> 9];
    }
  } else {
    for (int u = tid; u < 512; u += 256) {
      float s = bc1[u];
      for (int k=0;k<256;++k) s = fmaf(lnfb[k], Wc1[k*512+u], s);
      bc1f[u] = s;
    }
  }
}

// ---------------- LDS-free MFMA GEMM (QKV layer 0): C = A(bf16) x Bfrag(packed) ----------------
template<int NF, bool BIAS, bool RELU, bool OUTBF16, bool ACCUM>
__global__ __launch_bounds__(64) void k_gemm3(const short* __restrict__ A,
    const short* __restrict__ Bt, const float* __restrict__ bias, void* __restrict__ Cv,
    int outstride) {
  const int lane = threadIdx.x;
  const int q4 = lane >> 4, r = lane & 15;
  const int blockRow = blockIdx.x * 32;
  const int blockCol = blockIdx.y * (NF*16);
  float4v acc[2][NF];
  #pragma unroll
  for (int i=0;i<2;++i)
    #pragma unroll
    for (int j=0;j<NF;++j) acc[i][j] = (float4v){0,0,0,0};
  #pragma unroll
  for (int k0 = 0; k0 < 256; k0 += 32) {
    short8v a0 = *(const short8v*)&A[(size_t)(blockRow +      r)*CDIM + k0 + q4*8];
    short8v a1 = *(const short8v*)&A[(size_t)(blockRow + 16 + r)*CDIM + k0 + q4*8];
    #pragma unroll
    for (int nf=0; nf<NF; ++nf) {
      short8v bf = *(const short8v*)&Bt[(size_t)(((blockCol>>4) + nf)*8 + (k0>>5))*512 + lane*8];
      acc[0][nf] = mfma32(a0, bf, acc[0][nf]);
      acc[1][nf] = mfma32(a1, bf, acc[1][nf]);
    }
  }
  #pragma unroll
  for (int mf=0; mf<2; ++mf)
    #pragma unroll
    for (int nf=0; nf<NF; ++nf) {
      int col = blockCol + nf*16 + r;
      float bb = BIAS ? bias[col] : 0.f;
      #pragma unroll
      for (int reg=0; reg<4; ++reg) {
        int row = blockRow + mf*16 + q4*4 + reg;
        float v = acc[mf][nf][reg] + bb;
        if (RELU) v = fmaxf(v, 0.f);
        size_t oi = (size_t)row*outstride + col;
        if (ACCUM)        ((float*)Cv)[oi] += v;
        else if (OUTBF16) ((short*)Cv)[oi] = f2bs(v);
        else              ((float*)Cv)[oi] = v;
      }
    }
}

// ---------------- fused per-layer MLP: proj+res+LN1 -> FFN -> res+LN2 -> next-layer QKV ------
template<bool LAST>
__global__ __launch_bounds__(1024, 4) void k_mlp(
    const short* __restrict__ A,            // attn output rows (bf16, stride CDIM)
    const short* __restrict__ Bt,           // wpT layer l (fragment-packed)
    const float* __restrict__ bias,         // bproj layer l
    const short* __restrict__ W1t, const float* __restrict__ b1f,
    const short* __restrict__ W2t, const float* __restrict__ b2,
    float* __restrict__ X,                  // fp32 residual stream
    const short* __restrict__ Wqkv,         // qkvT layer l+1 (fragment-packed; unused if LAST)
    const float* __restrict__ bq,           // bq layer l+1   (unused if LAST)
    short* __restrict__ Qout) {             // qkvb           (unused if LAST)
  __shared__ __align__(16) short Ys[32*264];
  __shared__ __align__(16) short Gs[32*264];
  __shared__ float S1[32][16], S2[32][16];
  const int tid = threadIdx.x;
  const int w = tid >> 6, lane = tid & 63;
  const int q4 = lane >> 4, r = lane & 15;
  const int row0 = blockIdx.x * 32;
  const int colw = w*16 + r;               // this wave's output column, phases A/B

  // ===== stage A tile (32x256 bf16 = 16KB) into Gs, fully coalesced =====
  {
    short8v av = *(const short8v*)&A[(size_t)row0*CDIM + tid*8];
    *(short8v*)&Gs[(tid>>5)*264 + (tid&31)*8] = av;
  }
  __syncthreads();

  // ===== Phase A: proj GEMM (A from LDS, B packed) =====
  float4v acc0 = {0,0,0,0}, acc1 = {0,0,0,0};
  #pragma unroll
  for (int k=0;k<8;++k) {
    short8v b  = *(const short8v*)&Bt[(size_t)(w*8+k)*512 + lane*8];
    short8v a0 = *(const short8v*)&Gs[(     r)*264 + k*32 + q4*8];
    short8v a1 = *(const short8v*)&Gs[(16 + r)*264 + k*32 + q4*8];
    acc0 = mfma32(a0, b, acc0);
    acc1 = mfma32(a1, b, acc1);
  }
  float xv0[4], xv1[4];
  {
    float bb = bias[colw];
    #pragma unroll
    for (int reg=0; reg<4; ++reg) {
      float t0 = acc0[reg] + bb + X[(size_t)(row0 +      q4*4 + reg)*CDIM + colw];
      float t1 = acc1[reg] + bb + X[(size_t)(row0 + 16 + q4*4 + reg)*CDIM + colw];
      xv0[reg] = t0; xv1[reg] = t1;
      float s10 = t0, s20 = t0*t0, s11 = t1, s21 = t1*t1;
      #pragma unroll
      for (int off=1; off<16; off<<=1) {
        s10 += __shfl_xor(s10, off, 64); s20 += __shfl_xor(s20, off, 64);
        s11 += __shfl_xor(s11, off, 64); s21 += __shfl_xor(s21, off, 64);
      }
      if (r == 0) {
        S1[     q4*4 + reg][w] = s10; S2[     q4*4 + reg][w] = s20;
        S1[16 + q4*4 + reg][w] = s11; S2[16 + q4*4 + reg][w] = s21;
      }
    }
  }
  __syncthreads();
  // LN1 -> Ys
  #pragma unroll
  for (int reg=0; reg<4; ++reg) {
    int r0i = q4*4 + reg, r1i = 16 + q4*4 + reg;
    float s1=0.f, s2=0.f, t1=0.f, t2=0.f;
    #pragma unroll
    for (int j=0;j<16;++j) { s1 += S1[r0i][j]; s2 += S2[r0i][j]; t1 += S1[r1i][j]; t2 += S2[r1i][j]; }
    float mean = s1*(1.f/CDIM);
    float inv  = rsqrtf(s2*(1.f/CDIM) - mean*mean + 1e-5f);
    Ys[r0i*264 + colw] = f2bs(fmaf(xv0[reg], inv, -mean*inv));
    float mean2 = t1*(1.f/CDIM);
    float inv2  = rsqrtf(t2*(1.f/CDIM) - mean2*mean2 + 1e-5f);
    Ys[r1i*264 + colw] = f2bs(fmaf(xv1[reg], inv2, -mean2*inv2));
  }
  __syncthreads();

  // ===== FFN1: A from Ys, B packed -> relu -> Gs =====
  acc0 = (float4v){0,0,0,0}; acc1 = (float4v){0,0,0,0};
  #pragma unroll
  for (int k=0;k<8;++k) {
    short8v b  = *(const short8v*)&W1t[(size_t)(w*8+k)*512 + lane*8];
    short8v a0 = *(const short8v*)&Ys[(     r)*264 + k*32 + q4*8];
    short8v a1 = *(const short8v*)&Ys[(16 + r)*264 + k*32 + q4*8];
    acc0 = mfma32(a0, b, acc0);
    acc1 = mfma32(a1, b, acc1);
  }
  {
    float g = b1f[colw];
    #pragma unroll
    for (int reg=0; reg<4; ++reg) {
      Gs[(     q4*4 + reg)*264 + colw] = f2bs(fmaxf(acc0[reg] + g, 0.f));
      Gs[(16 + q4*4 + reg)*264 + colw] = f2bs(fmaxf(acc1[reg] + g, 0.f));
    }
  }
  __syncthreads();

  // ===== FFN2: A from Gs, B packed + residual [+ LN2 -> Ys] =====
  acc0 = (float4v){0,0,0,0}; acc1 = (float4v){0,0,0,0};
  #pragma unroll
  for (int k=0;k<8;++k) {
    short8v b  = *(const short8v*)&W2t[(size_t)(w*8+k)*512 + lane*8];
    short8v a0 = *(const short8v*)&Gs[(     r)*264 + k*32 + q4*8];
    short8v a1 = *(const short8v*)&Gs[(16 + r)*264 + k*32 + q4*8];
    acc0 = mfma32(a0, b, acc0);
    acc1 = mfma32(a1, b, acc1);
  }
  {
    float bb2 = b2[colw];
    #pragma unroll
    for (int reg=0; reg<4; ++reg) {
      float t0 = acc0[reg] + bb2 + xv0[reg];
      float t1 = acc1[reg] + bb2 + xv1[reg];
      xv0[reg] = t0; xv1[reg] = t1;
      X[(size_t)(row0 +      q4*4 + reg)*CDIM + colw] = t0;
      X[(size_t)(row0 + 16 + q4*4 + reg)*CDIM + colw] = t1;
      if (!LAST) {
        float s10 = t0, s20 = t0*t0, s11 = t1, s21 = t1*t1;
        #pragma unroll
        for (int off=1; off<16; off<<=1) {
          s10 += __shfl_xor(s10, off, 64); s20 += __shfl_xor(s20, off, 64);
          s11 += __shfl_xor(s11, off, 64); s21 += __shfl_xor(s21, off, 64);
        }
        if (r == 0) {
          S1[     q4*4 + reg][w] = s10; S2[     q4*4 + reg][w] = s20;
          S1[16 + q4*4 + reg][w] = s11; S2[16 + q4*4 + reg][w] = s21;
        }
      }
    }
  }
  if (LAST) return;
  __syncthreads();
  // LN2 -> Ys
  #pragma unroll
  for (int reg=0; reg<4; ++reg) {
    int r0i = q4*4 + reg, r1i = 16 + q4*4 + reg;
    float s1=0.f, s2=0.f, t1=0.f, t2=0.f;
    #pragma unroll
    for (int j=0;j<16;++j) { s1 += S1[r0i][j]; s2 += S2[r0i][j]; t1 += S1[r1i][j]; t2 += S2[r1i][j]; }
    float mean = s1*(1.f/CDIM);
    float inv  = rsqrtf(s2*(1.f/CDIM) - mean*mean + 1e-5f);
    Ys[r0i*264 + colw] = f2bs(fmaf(xv0[reg], inv, -mean*inv));
    float mean2 = t1*(1.f/CDIM);
    float inv2  = rsqrtf(t2*(1.f/CDIM) - mean2*mean2 + 1e-5f);
    Ys[r1i*264 + colw] = f2bs(fmaf(xv1[reg], inv2, -mean2*inv2));
  }
  __syncthreads();

  // ===== Phase C: next-layer QKV GEMM (A from Ys, B packed), wave = 32 rows x 48 cols =====
  {
    float4v qa0[3], qa1[3];
    #pragma unroll
    for (int j=0;j<3;++j) { qa0[j] = (float4v){0,0,0,0}; qa1[j] = (float4v){0,0,0,0}; }
    #pragma unroll
    for (int k=0;k<8;++k) {
      short8v ay0 = *(const short8v*)&Ys[(     r)*264 + k*32 + q4*8];
      short8v ay1 = *(const short8v*)&Ys[(16 + r)*264 + k*32 + q4*8];
      #pragma unroll
      for (int nf=0; nf<3; ++nf) {
        short8v b = *(const short8v*)&Wqkv[(size_t)((w*3+nf)*8 + k)*512 + lane*8];
        qa0[nf] = mfma32(ay0, b, qa0[nf]);
        qa1[nf] = mfma32(ay1, b, qa1[nf]);
      }
    }
    #pragma unroll
    for (int nf=0; nf<3; ++nf) {
      int col = (w*3+nf)*16 + r;
      float bb = bq[col];
      #pragma unroll
      for (int reg=0; reg<4; ++reg) {
        Qout[(size_t)(row0 +      q4*4 + reg)*QSTR + col] = f2bs(qa0[nf][reg] + bb);
        Qout[(size_t)(row0 + 16 + q4*4 + reg)*QSTR + col] = f2bs(qa1[nf][reg] + bb);
      }
    }
  }
}

// ---------------- MFMA flash attention: 128-key tiles, dbuf; l via ones-column MFMA ----------
#define KSS 40
#define VTS 140
__global__ __launch_bounds__(512) void k_attn6(const short* __restrict__ qkv,
    short* __restrict__ O) {
  __shared__ __align__(16) short Ks[2][128*KSS];
  __shared__ __align__(16) short Vt[2][32*VTS];
  const int tid = threadIdx.x;
  const int w = tid >> 6, lane = tid & 63;
  const int q4 = lane >> 4, r = lane & 15;
  const int b = blockIdx.z, h = blockIdx.y;
  const int rowbase = blockIdx.x*128 + w*16;
  short8v Qf = *(const short8v*)&qkv[((size_t)(b*TDIM + rowbase + r))*QSTR + h*HSZ + q4*8];
  float4v o0 = {0,0,0,0}, o1 = {0,0,0,0}, o2 = {0,0,0,0};
  const short ONE = (short)0x3F80;         // bf16 1.0
  const short4v ones = {ONE, ONE, ONE, ONE};
  const bool isV = tid >= 256;
  const int t2 = tid & 255;
  const int kkey = t2 >> 1, kd0 = (t2 & 1)*16;
  const int kp = t2 & 63, dg = t2 >> 6;
  const short* kvbase = qkv + (size_t)b*TDIM*QSTR + h*HSZ;
  short8v ka, kb2, va, vb;
  if (isV) {
    va = *(const short8v*)&kvbase[(size_t)(2*kp)*QSTR   + 2*CDIM + dg*8];
    vb = *(const short8v*)&kvbase[(size_t)(2*kp+1)*QSTR + 2*CDIM + dg*8];
  } else {
    ka  = *(const short8v*)&kvbase[(size_t)kkey*QSTR + CDIM + kd0];
    kb2 = *(const short8v*)&kvbase[(size_t)kkey*QSTR + CDIM + kd0 + 8];
  }
  int p = 0;
  for (int s0 = 0; s0 < TDIM; s0 += 128, p ^= 1) {
    if (isV) {
      union { short8v s; unsigned u[4]; } A, C;
      A.s = va; C.s = vb;
      #pragma unroll
      for (int j=0;j<4;++j) {
        *(unsigned*)&Vt[p][(dg*8+2*j  )*VTS + 2*kp] = __builtin_amdgcn_perm(C.u[j], A.u[j], 0x05040100u);
        *(unsigned*)&Vt[p][(dg*8+2*j+1)*VTS + 2*kp] = __builtin_amdgcn_perm(C.u[j], A.u[j], 0x07060302u);
      }
    } else {
      *(short8v*)&Ks[p][kkey*KSS + kd0]     = ka;
      *(short8v*)&Ks[p][kkey*KSS + kd0 + 8] = kb2;
    }
    if (s0 + 128 < TDIM) {
      const short* nb = kvbase + (size_t)(s0+128)*QSTR;
      if (isV) {
        va = *(const short8v*)&nb[(size_t)(2*kp)*QSTR   + 2*CDIM + dg*8];
        vb = *(const short8v*)&nb[(size_t)(2*kp+1)*QSTR + 2*CDIM + dg*8];
      } else {
        ka  = *(const short8v*)&nb[(size_t)kkey*QSTR + CDIM + kd0];
        kb2 = *(const short8v*)&nb[(size_t)kkey*QSTR + CDIM + kd0 + 8];
      }
    }
    __syncthreads();
    #pragma unroll
    for (int ks = 0; ks < 8; ++ks) {
      short8v Kf = *(const short8v*)&Ks[p][(ks*16 + r)*KSS + q4*8];
      float4v sv = mfma32(Kf, Qf, (float4v){0,0,0,0});
      short4v Vf0 = *(const short4v*)&Vt[p][r*VTS + ks*16 + q4*4];
      short4v Vf1 = *(const short4v*)&Vt[p][(16+r)*VTS + ks*16 + q4*4];
      float p0 = fexp2(sv[0]), p1 = fexp2(sv[1]);
      float p2 = fexp2(sv[2]), p3 = fexp2(sv[3]);
      union { unsigned u[2]; short4v s; } P;
      P.u[0] = pkbf(p0, p1); P.u[1] = pkbf(p2, p3);
      o0 = mfma16(P.s, Vf0, o0);
      o1 = mfma16(P.s, Vf1, o1);
      o2 = mfma16(P.s, ones, o2);
    }
  }
  #pragma unroll
  for (int reg=0; reg<4; ++reg) {
    float i0 = 1.f / o2[reg];
    short* op = O + ((size_t)(b*TDIM + rowbase + q4*4 + reg))*CDIM + h*HSZ;
    op[r]    = f2bs(o0[reg]*i0);
    op[16+r] = f2bs(o1[reg]*i0);
  }
}

// ---------------- fused final-LN + mean-pool ----------------
__global__ __launch_bounds__(256) void k_poolln(const float* __restrict__ X, float* __restrict__ part) {
  __shared__ float red[4][256];
  int b = blockIdx.x >> 3, chunk = blockIdx.x & 7;
  int wv = threadIdx.x >> 6, lane = threadIdx.x & 63;
  int base = b*TDIM + chunk*256 + wv*64;
  float a0=0,a1=0,a2=0,a3=0;
  for (int rr=0; rr<64; ++rr) {
    float4 v = *(const float4*)&X[(size_t)(base+rr)*CDIM + lane*4];
    float s1 = (v.x+v.y)+(v.z+v.w);
    float s2 = fmaf(v.x,v.x, fmaf(v.y,v.y, fmaf(v.z,v.z, v.w*v.w)));
    #pragma unroll
    for (int off=32; off>0; off>>=1) { s1 += __shfl_xor(s1,off,64); s2 += __shfl_xor(s2,off,64); }
    float mean = s1*(1.f/256.f);
    float inv  = rsqrtf(s2*(1.f/256.f) - mean*mean + 1e-5f);
    a0 = fmaf(v.x-mean, inv, a0); a1 = fmaf(v.y-mean, inv, a1);
    a2 = fmaf(v.z-mean, inv, a2); a3 = fmaf(v.w-mean, inv, a3);
  }
  red[wv][lane*4+0]=a0; red[wv][lane*4+1]=a1; red[wv][lane*4+2]=a2; red[wv][lane*4+3]=a3;
  __syncthreads();
  int c = threadIdx.x;
  part[blockIdx.x*256 + c] = (red[0][c]+red[1][c]+red[2][c]+red[3][c]) * (1.f/2048.f);
}

// ---------------- fused classifier ----------------
__global__ __launch_bounds__(512) void k_cls(const float* __restrict__ part,
    const float* __restrict__ Wc1s, const float* __restrict__ bc1f,
    const float* __restrict__ Wc2, const float* __restrict__ bc2, float* __restrict__ out) {
  __shared__ float se[4][256];
  __shared__ float sh[4][512];
  __shared__ float red[160];
  __shared__ float sl[40];
  const int t = threadIdx.x;
  for (int j=t; j<1024; j+=512) {
    int b = j >> 8, c = j & 255;
    float s = 0.f;
    #pragma unroll
    for (int ch=0; ch<8; ++ch) s += part[(b*8+ch)*256 + c];
    se[b][c] = s;
  }
  __syncthreads();
  {
    float bb = bc1f[t];
    float a0=bb, a1=bb, a2=bb, a3=bb;
    for (int c=0; c<256; ++c) {
      float w2 = Wc1s[c*512 + t];
      a0 = fmaf(se[0][c], w2, a0); a1 = fmaf(se[1][c], w2, a1);
      a2 = fmaf(se[2][c], w2, a2); a3 = fmaf(se[3][c], w2, a3);
    }
    sh[0][t]=fmaxf(a0,0.f); sh[1][t]=fmaxf(a1,0.f);
    sh[2][t]=fmaxf(a2,0.f); sh[3][t]=fmaxf(a3,0.f);
  }
  __syncthreads();
  if (t < 160) {
    int o = t >> 2, pp = t & 3;
    int b = o / 10, j = o - b*10;
    const float* hp = &sh[b][pp*128];
    float s = 0.f;
    #pragma unroll 8
    for (int u=0; u<128; ++u) s = fmaf(hp[u], Wc2[(pp*128+u)*10 + j], s);
    red[t] = s;
  }
  __syncthreads();
  if (t < 40) sl[t] = (red[t*4]+red[t*4+1]) + (red[t*4+2]+red[t*4+3]) + bc2[t%10];
  __syncthreads();
  if (t < 4) {
    float mx = -1e30f;
    for (int j=0;j<10;++j) mx = fmaxf(mx, sl[t*10+j]);
    float e[10], sum = 0.f;
    for (int j=0;j<10;++j) { e[j] = __expf(sl[t*10+j]-mx); sum += e[j]; }
    float inv = 1.f/sum;
    for (int j=0;j<10;++j) out[t*10+j] = e[j]*inv;
  }
}

extern "C" void kernel_launch(void* const* d_in, const int* in_sizes, int n_in,
                              void* d_out, int out_size, void* d_ws, size_t ws_size,
                              hipStream_t stream) {
  const int*   idx = (const int*)d_in[0];
  const float* tok = (const float*)d_in[1];
  const float* pos = (const float*)d_in[2];
  const float* Wq  = (const float*)d_in[3];
  const float* Wk  = (const float*)d_in[4];
  const float* Wv  = (const float*)d_in[5];
  const float* Wp  = (const float*)d_in[6];
  const float* bp  = (const float*)d_in[7];
  const float* l1g = (const float*)d_in[8];
  const float* l1b = (const float*)d_in[9];
  const float* l2g = (const float*)d_in[10];
  const float* l2b = (const float*)d_in[11];
  const float* W1  = (const float*)d_in[12];
  const float* b1  = (const float*)d_in[13];
  const float* W2  = (const float*)d_in[14];
  const float* b2  = (const float*)d_in[15];
  const float* lfg = (const float*)d_in[16];
  const float* lfb = (const float*)d_in[17];
  const float* Wc1 = (const float*)d_in[18];
  const float* bc1 = (const float*)d_in[19];
  const float* Wc2 = (const float*)d_in[20];
  const float* bc2 = (const float*)d_in[21];

  char* p = (char*)d_ws;
  float* xb   = (float*)p;              p += (size_t)BUF*4;
  short* hb   = (short*)p;              p += (size_t)BUF*2;
  short* qkvb = (short*)p;              p += (size_t)NTOK*QSTR*2;
  float* part = (float*)p;              p += 32*256*4;
  short* wqkvT = (short*)p;             p += (size_t)LNUM*QSTR*256*2;
  short* wpT   = (short*)p;             p += (size_t)LNUM*65536*2;
  short* w1T   = (short*)p;             p += (size_t)LNUM*65536*2;
  short* w2T   = (short*)p;             p += (size_t)LNUM*65536*2;
  float* bq    = (float*)p;             p += (size_t)LNUM*768*4;
  float* b1f   = (float*)p;             p += (size_t)LNUM*256*4;
  float* Wc1s  = (float*)p;             p += (size_t)256*512*4;
  float* bc1f  = (float*)p;             p += 512*4;

  k_prep_embed<<<513 + NTOK/4, 256, 0, stream>>>(idx, tok, pos,
                                   Wq, Wk, Wv, Wp, W1, W2, l1g, l2g, l1b, l2b,
                                   b1, Wc1, lfg, lfb, bc1,
                                   wqkvT, wpT, w1T, w2T, bq, b1f, Wc1s, bc1f,
                                   xb, hb);
  k_gemm3<4,true,false,true,false><<<dim3(256,12), 64, 0, stream>>>(
      hb, wqkvT, bq, qkvb, QSTR);
  for (int l = 0; l < LNUM; ++l) {
    k_attn6<<<dim3(16, HDIM, BDIM), 512, 0, stream>>>(qkvb, hb);
    if (l < LNUM-1) {
      k_mlp<false><<<256, 1024, 0, stream>>>(
          hb, wpT + (size_t)l*65536, bp + l*CDIM,
          w1T + (size_t)l*65536, b1f + l*CDIM, w2T + (size_t)l*65536, b2 + l*CDIM,
          xb,
          wqkvT + (size_t)(l+1)*QSTR*256, bq + (l+1)*768, qkvb);
    } else {
      k_mlp<true><<<256, 1024, 0, stream>>>(
          hb, wpT + (size_t)l*65536, bp + l*CDIM,
          w1T + (size_t)l*65536, b1f + l*CDIM, w2T + (size_t)l*65536, b2 + l*CDIM,
          xb,
          wqkvT, bq, qkvb);
    }
  }
  k_poolln<<<32, 256, 0, stream>>>(xb, part);
  k_cls<<<1, 512, 0, stream>>>(part, Wc1s, bc1f, Wc2, bc2, (float*)d_out);
}

// Round 13
// 436.956 us; speedup vs baseline: 1.1651x; 1.0424x over previous
//
#include <hip/hip_runtime.h>
#include <hip/hip_bf16.h>

#define NTOK 8192      // B*T
#define CDIM 256
#define TDIM 2048
#define BDIM 4
#define HDIM 8
#define HSZ  32
#define LNUM 4
#define BUF  (NTOK*CDIM)
#define QSTR 768       // fused qkv row stride
#define LC   0.0901684400056f   // 2^-4 * log2(e), folded into Wq/bq

typedef __attribute__((ext_vector_type(8))) short short8v;
typedef __attribute__((ext_vector_type(4))) short short4v;
typedef __attribute__((ext_vector_type(4))) float float4v;

// ---- fp32 -> bf16 pack helpers ----
#if __has_builtin(__builtin_amdgcn_cvt_pk_bf16_f32)
static __device__ __forceinline__ unsigned pkbf(float a, float b){
  auto t = __builtin_amdgcn_cvt_pk_bf16_f32(a, b);
  union { decltype(t) v; unsigned u; } cv; cv.v = t;
  return cv.u;
}
static __device__ __forceinline__ short f2bs(float f){
  auto t = __builtin_amdgcn_cvt_pk_bf16_f32(f, f);
  union { decltype(t) v; unsigned u; } cv; cv.v = t;
  return (short)(cv.u & 0xFFFFu);
}
#else
static __device__ __forceinline__ short f2bs(float f){
  union { float f; unsigned u; } x; x.f = f;
  unsigned r = x.u + 0x7FFFu + ((x.u >> 16) & 1u);
  return (short)(r >> 16);
}
static __device__ __forceinline__ unsigned pkbf(float a, float b){
  union { float f; unsigned u; } x, y; x.f = a; y.f = b;
  unsigned ra = x.u + 0x7FFFu + ((x.u >> 16) & 1u);
  unsigned rb = y.u + 0x7FFFu + ((y.u >> 16) & 1u);
  return __builtin_amdgcn_perm(rb, ra, 0x07060302u);
}
#endif
#if __has_builtin(__builtin_amdgcn_exp2f)
static __device__ __forceinline__ float fexp2(float x){ return __builtin_amdgcn_exp2f(x); }
#else
static __device__ __forceinline__ float fexp2(float x){ return __expf(x*0.6931471805599453f); }
#endif

#if __has_builtin(__builtin_amdgcn_mfma_f32_16x16x16bf16_1k)
static __device__ __forceinline__ float4v mfma16(short4v a, short4v b, float4v c){
  return __builtin_amdgcn_mfma_f32_16x16x16bf16_1k(a, b, c, 0, 0, 0);
}
#else
static __device__ __forceinline__ float4v mfma16(short4v a, short4v b, float4v c){
  float4v d;
  asm volatile("v_mfma_f32_16x16x16_bf16 %0, %1, %2, %3\n\ts_nop 7\n\ts_nop 7"
               : "=v"(d) : "v"(a), "v"(b), "v"(c));
  return d;
}
#endif
static __device__ __forceinline__ float4v mfma32(short8v a, short8v b, float4v c){
  return __builtin_amdgcn_mfma_f32_16x16x32_bf16(a, b, c, 0, 0, 0);
}

// fragment-packed weight address: value (n,k) -> cg=n>>4, ks=k>>5, lane=((k>>3)&3)*16+(n&15), j=k&7
static __device__ __forceinline__ int faddr(int n, int k){
  return ((n>>4)*8 + (k>>5))*512 + ((((k>>3)&3)<<4) + (n&15))*8 + (k&7);
}

// ---------------- merged weight prep + bias folding + embedding + LN1(layer0) ----------------
__global__ __launch_bounds__(256) void k_prep_embed(
    const int* __restrict__ idx, const float* __restrict__ tok, const float* __restrict__ pos,
    const float* __restrict__ Wq, const float* __restrict__ Wk, const float* __restrict__ Wv,
    const float* __restrict__ Wp, const float* __restrict__ W1, const float* __restrict__ W2,
    const float* __restrict__ l1g, const float* __restrict__ l2g,
    const float* __restrict__ l1b, const float* __restrict__ l2b,
    const float* __restrict__ b1, const float* __restrict__ Wc1, const float* __restrict__ lnfg,
    const float* __restrict__ lnfb, const float* __restrict__ bc1,
    short* __restrict__ qkvT, short* __restrict__ wpT, short* __restrict__ w1T, short* __restrict__ w2T,
    float* __restrict__ bq, float* __restrict__ b1f, float* __restrict__ Wc1s, float* __restrict__ bc1f,
    float* __restrict__ x, short* __restrict__ y) {
  const int tid = threadIdx.x;
  const int id = blockIdx.x;
  if (id >= 513) {
    // ---- embedding + LN path ----
    const int bid = id - 513;
    const int lane = tid & 63;
    const int bt = bid*4 + (tid >> 6);
    const int t = bt & (TDIM-1);
    float4 tv = *(const float4*)&tok[(size_t)idx[bt]*CDIM + lane*4];
    float4 pv = *(const float4*)&pos[(size_t)t*CDIM + lane*4];
    float4 v = make_float4(tv.x+pv.x, tv.y+pv.y, tv.z+pv.z, tv.w+pv.w);
    *(float4*)&x[(size_t)bt*CDIM + lane*4] = v;
    float s1 = (v.x+v.y) + (v.z+v.w);
    float s2 = fmaf(v.x,v.x, fmaf(v.y,v.y, fmaf(v.z,v.z, v.w*v.w)));
    #pragma unroll
    for (int off=32; off>0; off>>=1) { s1 += __shfl_xor(s1, off, 64); s2 += __shfl_xor(s2, off, 64); }
    float mean = s1*(1.f/CDIM);
    float inv  = rsqrtf(s2*(1.f/CDIM) - mean*mean + 1e-5f);
    float cc = -mean*inv;
    union { unsigned u[2]; short4v s; } o;
    o.u[0] = pkbf(fmaf(v.x,inv,cc), fmaf(v.y,inv,cc));
    o.u[1] = pkbf(fmaf(v.z,inv,cc), fmaf(v.w,inv,cc));
    *(short4v*)&y[(size_t)bt*CDIM + lane*4] = o.s;
    return;
  }
  if (id < 384) {
    __shared__ float tile[64][65];
    int l = id / 96, rr = id % 96;
    const float* src; short* dst; int n0, k0; bool qkvmode; int gsel; float nscale = 1.f;
    if (rr < 48) {
      int tn = rr >> 2, tk = rr & 3;
      n0 = tn*64; k0 = tk*64;
      const float* b3 = (n0 < 256) ? Wq : (n0 < 512 ? Wk : Wv);
      src = b3 + l*65536;
      dst = qkvT + (size_t)l*QSTR*256;
      qkvmode = true; gsel = 1;
      if (n0 < 256) nscale = LC;
    } else {
      int r2 = rr - 48;
      int mat = r2 >> 4, t = r2 & 15;
      int tn = t >> 2, tk = t & 3;
      n0 = tn*64; k0 = tk*64;
      const float* b3 = (mat == 0) ? Wp : (mat == 1 ? W1 : W2);
      src = b3 + l*65536;
      dst = (mat == 0 ? wpT : (mat == 1 ? w1T : w2T)) + l*65536;
      qkvmode = false; gsel = (mat == 1) ? 2 : 0;
    }
    const int cn = tid & 63, rk = tid >> 6;
    #pragma unroll
    for (int i = 0; i < 16; ++i) {
      int kk = rk + i*4;
      int n = n0 + cn, k = k0 + kk;
      float v;
      if (qkvmode) { int nn = n & 255; v = src[((nn>>5)*256 + k)*32 + (nn & 31)]; }
      else         { v = src[k*256 + n]; }
      if (gsel == 1)      v *= l1g[l*256 + k];
      else if (gsel == 2) v *= l2g[l*256 + k];
      tile[kk][cn] = v;
    }
    __syncthreads();
    #pragma unroll
    for (int i = 0; i < 16; ++i) {
      int nn = rk + i*4;
      dst[faddr(n0 + nn, k0 + cn)] = f2bs(tile[cn][nn] * nscale);
    }
  } else if (id < 448) {
    __shared__ float red[4][64];
    int bid = id - 384;
    int l = bid >> 4, seg = bid & 15;
    int o = seg*64 + (tid & 63), pp = tid >> 6;
    float s = 0.f;
    if (o < 768) {
      const float* W = (o < 256 ? Wq : (o < 512 ? Wk : Wv)) + l*65536;
      int nn = o & 255, h = nn >> 5, d = nn & 31;
      const float* bv = l1b + l*256;
      for (int k = pp*64; k < pp*64+64; ++k) s = fmaf(bv[k], W[(h*256 + k)*32 + d], s);
    } else {
      const float* W = W1 + l*65536;
      int n = o - 768;
      const float* bv = l2b + l*256;
      for (int k = pp*64; k < pp*64+64; ++k) s = fmaf(bv[k], W[k*256 + n], s);
    }
    red[pp][tid & 63] = s;
    __syncthreads();
    if (tid < 64) {
      float tot = red[0][tid]+red[1][tid]+red[2][tid]+red[3][tid];
      int oo = seg*64 + tid;
      if (oo < 768) bq[l*768 + oo] = tot * (oo < 256 ? LC : 1.f);
      else          b1f[l*256 + (oo-768)] = b1[l*256 + (oo-768)] + tot;
    }
  } else if (id < 512) {
    int base = (id-448)*2048;
    #pragma unroll
    for (int i=0;i<8;++i) {
      int idx2 = base + i*256 + tid;
      Wc1s[idx2] = Wc1[idx2] * lnfg[idx2 >> 9];
    }
  } else {
    for (int u = tid; u < 512; u += 256) {
      float s = bc1[u];
      for (int k=0;k<256;++k) s = fmaf(lnfb[k], Wc1[k*512+u], s);
      bc1f[u] = s;
    }
  }
}

// ---------------- LDS-free MFMA GEMM (QKV layer 0): C = A(bf16) x Bfrag(packed) ----------------
template<int NF, bool BIAS, bool RELU, bool OUTBF16, bool ACCUM>
__global__ __launch_bounds__(64) void k_gemm3(const short* __restrict__ A,
    const short* __restrict__ Bt, const float* __restrict__ bias, void* __restrict__ Cv,
    int outstride) {
  const int lane = threadIdx.x;
  const int q4 = lane >> 4, r = lane & 15;
  const int blockRow = blockIdx.x * 32;
  const int blockCol = blockIdx.y * (NF*16);
  float4v acc[2][NF];
  #pragma unroll
  for (int i=0;i<2;++i)
    #pragma unroll
    for (int j=0;j<NF;++j) acc[i][j] = (float4v){0,0,0,0};
  #pragma unroll
  for (int k0 = 0; k0 < 256; k0 += 32) {
    short8v a0 = *(const short8v*)&A[(size_t)(blockRow +      r)*CDIM + k0 + q4*8];
    short8v a1 = *(const short8v*)&A[(size_t)(blockRow + 16 + r)*CDIM + k0 + q4*8];
    #pragma unroll
    for (int nf=0; nf<NF; ++nf) {
      short8v bf = *(const short8v*)&Bt[(size_t)(((blockCol>>4) + nf)*8 + (k0>>5))*512 + lane*8];
      acc[0][nf] = mfma32(a0, bf, acc[0][nf]);
      acc[1][nf] = mfma32(a1, bf, acc[1][nf]);
    }
  }
  #pragma unroll
  for (int mf=0; mf<2; ++mf)
    #pragma unroll
    for (int nf=0; nf<NF; ++nf) {
      int col = blockCol + nf*16 + r;
      float bb = BIAS ? bias[col] : 0.f;
      #pragma unroll
      for (int reg=0; reg<4; ++reg) {
        int row = blockRow + mf*16 + q4*4 + reg;
        float v = acc[mf][nf][reg] + bb;
        if (RELU) v = fmaxf(v, 0.f);
        size_t oi = (size_t)row*outstride + col;
        if (ACCUM)        ((float*)Cv)[oi] += v;
        else if (OUTBF16) ((short*)Cv)[oi] = f2bs(v);
        else              ((float*)Cv)[oi] = v;
      }
    }
}

// ---------------- fused per-layer MLP: proj+res+LN1 -> FFN -> res+LN2 -> next-layer QKV ------
template<bool LAST>
__global__ __launch_bounds__(1024, 4) void k_mlp(
    const short* __restrict__ A,            // attn output rows (bf16, stride CDIM)
    const short* __restrict__ Bt,           // wpT layer l (fragment-packed)
    const float* __restrict__ bias,         // bproj layer l
    const short* __restrict__ W1t, const float* __restrict__ b1f,
    const short* __restrict__ W2t, const float* __restrict__ b2,
    float* __restrict__ X,                  // fp32 residual stream
    const short* __restrict__ Wqkv,         // qkvT layer l+1 (fragment-packed; unused if LAST)
    const float* __restrict__ bq,           // bq layer l+1   (unused if LAST)
    short* __restrict__ Qout) {             // qkvb           (unused if LAST)
  __shared__ __align__(16) short Ys[32*264];
  __shared__ __align__(16) short Gs[32*264];
  __shared__ __align__(16) float S1[32][20], S2[32][20];   // 20-stride: bank-safe, float4-aligned
  const int tid = threadIdx.x;
  const int w = tid >> 6, lane = tid & 63;
  const int q4 = lane >> 4, r = lane & 15;
  const int row0 = blockIdx.x * 32;
  const int colw = w*16 + r;               // this wave's output column, phases A/B

  // ===== stage A tile (32x256 bf16 = 16KB) into Gs, fully coalesced =====
  {
    short8v av = *(const short8v*)&A[(size_t)row0*CDIM + tid*8];
    *(short8v*)&Gs[(tid>>5)*264 + (tid&31)*8] = av;
  }
  __syncthreads();

  // ===== Phase A: proj GEMM (A from LDS, B packed) =====
  float4v acc0 = {0,0,0,0}, acc1 = {0,0,0,0};
  #pragma unroll
  for (int k=0;k<8;++k) {
    short8v b  = *(const short8v*)&Bt[(size_t)(w*8+k)*512 + lane*8];
    short8v a0 = *(const short8v*)&Gs[(     r)*264 + k*32 + q4*8];
    short8v a1 = *(const short8v*)&Gs[(16 + r)*264 + k*32 + q4*8];
    acc0 = mfma32(a0, b, acc0);
    acc1 = mfma32(a1, b, acc1);
  }
  float xv0[4], xv1[4];
  {
    float bb = bias[colw];
    #pragma unroll
    for (int reg=0; reg<4; ++reg) {
      float t0 = acc0[reg] + bb + X[(size_t)(row0 +      q4*4 + reg)*CDIM + colw];
      float t1 = acc1[reg] + bb + X[(size_t)(row0 + 16 + q4*4 + reg)*CDIM + colw];
      xv0[reg] = t0; xv1[reg] = t1;
      float s10 = t0, s20 = t0*t0, s11 = t1, s21 = t1*t1;
      #pragma unroll
      for (int off=1; off<16; off<<=1) {
        s10 += __shfl_xor(s10, off, 64); s20 += __shfl_xor(s20, off, 64);
        s11 += __shfl_xor(s11, off, 64); s21 += __shfl_xor(s21, off, 64);
      }
      if (r == 0) {
        S1[     q4*4 + reg][w] = s10; S2[     q4*4 + reg][w] = s20;
        S1[16 + q4*4 + reg][w] = s11; S2[16 + q4*4 + reg][w] = s21;
      }
    }
  }
  __syncthreads();
  // LN1 -> Ys (vector reduce over 16 wave-partials)
  #pragma unroll
  for (int reg=0; reg<4; ++reg) {
    int r0i = q4*4 + reg, r1i = 16 + q4*4 + reg;
    float s1=0.f, s2=0.f, t1=0.f, t2=0.f;
    #pragma unroll
    for (int j4=0;j4<4;++j4) {
      float4 a1v = *(const float4*)&S1[r0i][j4*4];
      float4 a2v = *(const float4*)&S2[r0i][j4*4];
      float4 b1v = *(const float4*)&S1[r1i][j4*4];
      float4 b2v = *(const float4*)&S2[r1i][j4*4];
      s1 += (a1v.x+a1v.y)+(a1v.z+a1v.w);
      s2 += (a2v.x+a2v.y)+(a2v.z+a2v.w);
      t1 += (b1v.x+b1v.y)+(b1v.z+b1v.w);
      t2 += (b2v.x+b2v.y)+(b2v.z+b2v.w);
    }
    float mean = s1*(1.f/CDIM);
    float inv  = rsqrtf(s2*(1.f/CDIM) - mean*mean + 1e-5f);
    Ys[r0i*264 + colw] = f2bs(fmaf(xv0[reg], inv, -mean*inv));
    float mean2 = t1*(1.f/CDIM);
    float inv2  = rsqrtf(t2*(1.f/CDIM) - mean2*mean2 + 1e-5f);
    Ys[r1i*264 + colw] = f2bs(fmaf(xv1[reg], inv2, -mean2*inv2));
  }
  __syncthreads();

  // ===== FFN1: A from Ys, B packed -> relu -> Gs =====
  acc0 = (float4v){0,0,0,0}; acc1 = (float4v){0,0,0,0};
  #pragma unroll
  for (int k=0;k<8;++k) {
    short8v b  = *(const short8v*)&W1t[(size_t)(w*8+k)*512 + lane*8];
    short8v a0 = *(const short8v*)&Ys[(     r)*264 + k*32 + q4*8];
    short8v a1 = *(const short8v*)&Ys[(16 + r)*264 + k*32 + q4*8];
    acc0 = mfma32(a0, b, acc0);
    acc1 = mfma32(a1, b, acc1);
  }
  {
    float g = b1f[colw];
    #pragma unroll
    for (int reg=0; reg<4; ++reg) {
      Gs[(     q4*4 + reg)*264 + colw] = f2bs(fmaxf(acc0[reg] + g, 0.f));
      Gs[(16 + q4*4 + reg)*264 + colw] = f2bs(fmaxf(acc1[reg] + g, 0.f));
    }
  }
  __syncthreads();

  // ===== FFN2: A from Gs, B packed + residual [+ LN2 -> Ys] =====
  acc0 = (float4v){0,0,0,0}; acc1 = (float4v){0,0,0,0};
  #pragma unroll
  for (int k=0;k<8;++k) {
    short8v b  = *(const short8v*)&W2t[(size_t)(w*8+k)*512 + lane*8];
    short8v a0 = *(const short8v*)&Gs[(     r)*264 + k*32 + q4*8];
    short8v a1 = *(const short8v*)&Gs[(16 + r)*264 + k*32 + q4*8];
    acc0 = mfma32(a0, b, acc0);
    acc1 = mfma32(a1, b, acc1);
  }
  {
    float bb2 = b2[colw];
    #pragma unroll
    for (int reg=0; reg<4; ++reg) {
      float t0 = acc0[reg] + bb2 + xv0[reg];
      float t1 = acc1[reg] + bb2 + xv1[reg];
      xv0[reg] = t0; xv1[reg] = t1;
      X[(size_t)(row0 +      q4*4 + reg)*CDIM + colw] = t0;
      X[(size_t)(row0 + 16 + q4*4 + reg)*CDIM + colw] = t1;
      if (!LAST) {
        float s10 = t0, s20 = t0*t0, s11 = t1, s21 = t1*t1;
        #pragma unroll
        for (int off=1; off<16; off<<=1) {
          s10 += __shfl_xor(s10, off, 64); s20 += __shfl_xor(s20, off, 64);
          s11 += __shfl_xor(s11, off, 64); s21 += __shfl_xor(s21, off, 64);
        }
        if (r == 0) {
          S1[     q4*4 + reg][w] = s10; S2[     q4*4 + reg][w] = s20;
          S1[16 + q4*4 + reg][w] = s11; S2[16 + q4*4 + reg][w] = s21;
        }
      }
    }
  }
  if (LAST) return;
  __syncthreads();
  // LN2 -> Ys (vector reduce)
  #pragma unroll
  for (int reg=0; reg<4; ++reg) {
    int r0i = q4*4 + reg, r1i = 16 + q4*4 + reg;
    float s1=0.f, s2=0.f, t1=0.f, t2=0.f;
    #pragma unroll
    for (int j4=0;j4<4;++j4) {
      float4 a1v = *(const float4*)&S1[r0i][j4*4];
      float4 a2v = *(const float4*)&S2[r0i][j4*4];
      float4 b1v = *(const float4*)&S1[r1i][j4*4];
      float4 b2v = *(const float4*)&S2[r1i][j4*4];
      s1 += (a1v.x+a1v.y)+(a1v.z+a1v.w);
      s2 += (a2v.x+a2v.y)+(a2v.z+a2v.w);
      t1 += (b1v.x+b1v.y)+(b1v.z+b1v.w);
      t2 += (b2v.x+b2v.y)+(b2v.z+b2v.w);
    }
    float mean = s1*(1.f/CDIM);
    float inv  = rsqrtf(s2*(1.f/CDIM) - mean*mean + 1e-5f);
    Ys[r0i*264 + colw] = f2bs(fmaf(xv0[reg], inv, -mean*inv));
    float mean2 = t1*(1.f/CDIM);
    float inv2  = rsqrtf(t2*(1.f/CDIM) - mean2*mean2 + 1e-5f);
    Ys[r1i*264 + colw] = f2bs(fmaf(xv1[reg], inv2, -mean2*inv2));
  }
  __syncthreads();

  // ===== Phase C: next-layer QKV GEMM (A from Ys, B packed), wave = 32 rows x 48 cols =====
  {
    float4v qa0[3], qa1[3];
    #pragma unroll
    for (int j=0;j<3;++j) { qa0[j] = (float4v){0,0,0,0}; qa1[j] = (float4v){0,0,0,0}; }
    #pragma unroll
    for (int k=0;k<8;++k) {
      short8v ay0 = *(const short8v*)&Ys[(     r)*264 + k*32 + q4*8];
      short8v ay1 = *(const short8v*)&Ys[(16 + r)*264 + k*32 + q4*8];
      #pragma unroll
      for (int nf=0; nf<3; ++nf) {
        short8v b = *(const short8v*)&Wqkv[(size_t)((w*3+nf)*8 + k)*512 + lane*8];
        qa0[nf] = mfma32(ay0, b, qa0[nf]);
        qa1[nf] = mfma32(ay1, b, qa1[nf]);
      }
    }
    #pragma unroll
    for (int nf=0; nf<3; ++nf) {
      int col = (w*3+nf)*16 + r;
      float bb = bq[col];
      #pragma unroll
      for (int reg=0; reg<4; ++reg) {
        Qout[(size_t)(row0 +      q4*4 + reg)*QSTR + col] = f2bs(qa0[nf][reg] + bb);
        Qout[(size_t)(row0 + 16 + q4*4 + reg)*QSTR + col] = f2bs(qa1[nf][reg] + bb);
      }
    }
  }
}

// ---------------- MFMA flash attention: 128-key tiles, dbuf; l via ones-column MFMA ----------
#define KSS 40
#define VTS 140
__global__ __launch_bounds__(512) void k_attn6(const short* __restrict__ qkv,
    short* __restrict__ O) {
  __shared__ __align__(16) short Ks[2][128*KSS];
  __shared__ __align__(16) short Vt[2][32*VTS];
  const int tid = threadIdx.x;
  const int w = tid >> 6, lane = tid & 63;
  const int q4 = lane >> 4, r = lane & 15;
  const int b = blockIdx.z, h = blockIdx.y;
  const int rowbase = blockIdx.x*128 + w*16;
  short8v Qf = *(const short8v*)&qkv[((size_t)(b*TDIM + rowbase + r))*QSTR + h*HSZ + q4*8];
  float4v o0 = {0,0,0,0}, o1 = {0,0,0,0}, o2 = {0,0,0,0};
  const short ONE = (short)0x3F80;         // bf16 1.0
  const short4v ones = {ONE, ONE, ONE, ONE};
  const bool isV = tid >= 256;
  const int t2 = tid & 255;
  const int kkey = t2 >> 1, kd0 = (t2 & 1)*16;
  const int kp = t2 & 63, dg = t2 >> 6;
  const short* kvbase = qkv + (size_t)b*TDIM*QSTR + h*HSZ;
  short8v ka, kb2, va, vb;
  if (isV) {
    va = *(const short8v*)&kvbase[(size_t)(2*kp)*QSTR   + 2*CDIM + dg*8];
    vb = *(const short8v*)&kvbase[(size_t)(2*kp+1)*QSTR + 2*CDIM + dg*8];
  } else {
    ka  = *(const short8v*)&kvbase[(size_t)kkey*QSTR + CDIM + kd0];
    kb2 = *(const short8v*)&kvbase[(size_t)kkey*QSTR + CDIM + kd0 + 8];
  }
  int p = 0;
  for (int s0 = 0; s0 < TDIM; s0 += 128, p ^= 1) {
    if (isV) {
      union { short8v s; unsigned u[4]; } A, C;
      A.s = va; C.s = vb;
      #pragma unroll
      for (int j=0;j<4;++j) {
        *(unsigned*)&Vt[p][(dg*8+2*j  )*VTS + 2*kp] = __builtin_amdgcn_perm(C.u[j], A.u[j], 0x05040100u);
        *(unsigned*)&Vt[p][(dg*8+2*j+1)*VTS + 2*kp] = __builtin_amdgcn_perm(C.u[j], A.u[j], 0x07060302u);
      }
    } else {
      *(short8v*)&Ks[p][kkey*KSS + kd0]     = ka;
      *(short8v*)&Ks[p][kkey*KSS + kd0 + 8] = kb2;
    }
    if (s0 + 128 < TDIM) {
      const short* nb = kvbase + (size_t)(s0+128)*QSTR;
      if (isV) {
        va = *(const short8v*)&nb[(size_t)(2*kp)*QSTR   + 2*CDIM + dg*8];
        vb = *(const short8v*)&nb[(size_t)(2*kp+1)*QSTR + 2*CDIM + dg*8];
      } else {
        ka  = *(const short8v*)&nb[(size_t)kkey*QSTR + CDIM + kd0];
        kb2 = *(const short8v*)&nb[(size_t)kkey*QSTR + CDIM + kd0 + 8];
      }
    }
    __syncthreads();
    #pragma unroll
    for (int ks = 0; ks < 8; ++ks) {
      short8v Kf = *(const short8v*)&Ks[p][(ks*16 + r)*KSS + q4*8];
      float4v sv = mfma32(Kf, Qf, (float4v){0,0,0,0});
      short4v Vf0 = *(const short4v*)&Vt[p][r*VTS + ks*16 + q4*4];
      short4v Vf1 = *(const short4v*)&Vt[p][(16+r)*VTS + ks*16 + q4*4];
      float p0 = fexp2(sv[0]), p1 = fexp2(sv[1]);
      float p2 = fexp2(sv[2]), p3 = fexp2(sv[3]);
      union { unsigned u[2]; short4v s; } P;
      P.u[0] = pkbf(p0, p1); P.u[1] = pkbf(p2, p3);
      o0 = mfma16(P.s, Vf0, o0);
      o1 = mfma16(P.s, Vf1, o1);
      o2 = mfma16(P.s, ones, o2);
    }
  }
  #pragma unroll
  for (int reg=0; reg<4; ++reg) {
    float i0 = 1.f / o2[reg];
    short* op = O + ((size_t)(b*TDIM + rowbase + q4*4 + reg))*CDIM + h*HSZ;
    op[r]    = f2bs(o0[reg]*i0);
    op[16+r] = f2bs(o1[reg]*i0);
  }
}

// ---------------- fused final-LN + mean-pool ----------------
__global__ __launch_bounds__(256) void k_poolln(const float* __restrict__ X, float* __restrict__ part) {
  __shared__ float red[4][256];
  int b = blockIdx.x >> 3, chunk = blockIdx.x & 7;
  int wv = threadIdx.x >> 6, lane = threadIdx.x & 63;
  int base = b*TDIM + chunk*256 + wv*64;
  float a0=0,a1=0,a2=0,a3=0;
  for (int rr=0; rr<64; ++rr) {
    float4 v = *(const float4*)&X[(size_t)(base+rr)*CDIM + lane*4];
    float s1 = (v.x+v.y)+(v.z+v.w);
    float s2 = fmaf(v.x,v.x, fmaf(v.y,v.y, fmaf(v.z,v.z, v.w*v.w)));
    #pragma unroll
    for (int off=32; off>0; off>>=1) { s1 += __shfl_xor(s1,off,64); s2 += __shfl_xor(s2,off,64); }
    float mean = s1*(1.f/256.f);
    float inv  = rsqrtf(s2*(1.f/256.f) - mean*mean + 1e-5f);
    a0 = fmaf(v.x-mean, inv, a0); a1 = fmaf(v.y-mean, inv, a1);
    a2 = fmaf(v.z-mean, inv, a2); a3 = fmaf(v.w-mean, inv, a3);
  }
  red[wv][lane*4+0]=a0; red[wv][lane*4+1]=a1; red[wv][lane*4+2]=a2; red[wv][lane*4+3]=a3;
  __syncthreads();
  int c = threadIdx.x;
  part[blockIdx.x*256 + c] = (red[0][c]+red[1][c]+red[2][c]+red[3][c]) * (1.f/2048.f);
}

// ---------------- fused classifier ----------------
__global__ __launch_bounds__(512) void k_cls(const float* __restrict__ part,
    const float* __restrict__ Wc1s, const float* __restrict__ bc1f,
    const float* __restrict__ Wc2, const float* __restrict__ bc2, float* __restrict__ out) {
  __shared__ float se[4][256];
  __shared__ float sh[4][512];
  __shared__ float red[160];
  __shared__ float sl[40];
  const int t = threadIdx.x;
  for (int j=t; j<1024; j+=512) {
    int b = j >> 8, c = j & 255;
    float s = 0.f;
    #pragma unroll
    for (int ch=0; ch<8; ++ch) s += part[(b*8+ch)*256 + c];
    se[b][c] = s;
  }
  __syncthreads();
  {
    float bb = bc1f[t];
    float a0=bb, a1=bb, a2=bb, a3=bb;
    for (int c=0; c<256; ++c) {
      float w2 = Wc1s[c*512 + t];
      a0 = fmaf(se[0][c], w2, a0); a1 = fmaf(se[1][c], w2, a1);
      a2 = fmaf(se[2][c], w2, a2); a3 = fmaf(se[3][c], w2, a3);
    }
    sh[0][t]=fmaxf(a0,0.f); sh[1][t]=fmaxf(a1,0.f);
    sh[2][t]=fmaxf(a2,0.f); sh[3][t]=fmaxf(a3,0.f);
  }
  __syncthreads();
  if (t < 160) {
    int o = t >> 2, pp = t & 3;
    int b = o / 10, j = o - b*10;
    const float* hp = &sh[b][pp*128];
    float s = 0.f;
    #pragma unroll 8
    for (int u=0; u<128; ++u) s = fmaf(hp[u], Wc2[(pp*128+u)*10 + j], s);
    red[t] = s;
  }
  __syncthreads();
  if (t < 40) sl[t] = (red[t*4]+red[t*4+1]) + (red[t*4+2]+red[t*4+3]) + bc2[t%10];
  __syncthreads();
  if (t < 4) {
    float mx = -1e30f;
    for (int j=0;j<10;++j) mx = fmaxf(mx, sl[t*10+j]);
    float e[10], sum = 0.f;
    for (int j=0;j<10;++j) { e[j] = __expf(sl[t*10+j]-mx); sum += e[j]; }
    float inv = 1.f/sum;
    for (int j=0;j<10;++j) out[t*10+j] = e[j]*inv;
  }
}

extern "C" void kernel_launch(void* const* d_in, const int* in_sizes, int n_in,
                              void* d_out, int out_size, void* d_ws, size_t ws_size,
                              hipStream_t stream) {
  const int*   idx = (const int*)d_in[0];
  const float* tok = (const float*)d_in[1];
  const float* pos = (const float*)d_in[2];
  const float* Wq  = (const float*)d_in[3];
  const float* Wk  = (const float*)d_in[4];
  const float* Wv  = (const float*)d_in[5];
  const float* Wp  = (const float*)d_in[6];
  const float* bp  = (const float*)d_in[7];
  const float* l1g = (const float*)d_in[8];
  const float* l1b = (const float*)d_in[9];
  const float* l2g = (const float*)d_in[10];
  const float* l2b = (const float*)d_in[11];
  const float* W1  = (const float*)d_in[12];
  const float* b1  = (const float*)d_in[13];
  const float* W2  = (const float*)d_in[14];
  const float* b2  = (const float*)d_in[15];
  const float* lfg = (const float*)d_in[16];
  const float* lfb = (const float*)d_in[17];
  const float* Wc1 = (const float*)d_in[18];
  const float* bc1 = (const float*)d_in[19];
  const float* Wc2 = (const float*)d_in[20];
  const float* bc2 = (const float*)d_in[21];

  char* p = (char*)d_ws;
  float* xb   = (float*)p;              p += (size_t)BUF*4;
  short* hb   = (short*)p;              p += (size_t)BUF*2;
  short* qkvb = (short*)p;              p += (size_t)NTOK*QSTR*2;
  float* part = (float*)p;              p += 32*256*4;
  short* wqkvT = (short*)p;             p += (size_t)LNUM*QSTR*256*2;
  short* wpT   = (short*)p;             p += (size_t)LNUM*65536*2;
  short* w1T   = (short*)p;             p += (size_t)LNUM*65536*2;
  short* w2T   = (short*)p;             p += (size_t)LNUM*65536*2;
  float* bq    = (float*)p;             p += (size_t)LNUM*768*4;
  float* b1f   = (float*)p;             p += (size_t)LNUM*256*4;
  float* Wc1s  = (float*)p;             p += (size_t)256*512*4;
  float* bc1f  = (float*)p;             p += 512*4;

  k_prep_embed<<<513 + NTOK/4, 256, 0, stream>>>(idx, tok, pos,
                                   Wq, Wk, Wv, Wp, W1, W2, l1g, l2g, l1b, l2b,
                                   b1, Wc1, lfg, lfb, bc1,
                                   wqkvT, wpT, w1T, w2T, bq, b1f, Wc1s, bc1f,
                                   xb, hb);
  k_gemm3<4,true,false,true,false><<<dim3(256,12), 64, 0, stream>>>(
      hb, wqkvT, bq, qkvb, QSTR);
  for (int l = 0; l < LNUM; ++l) {
    k_attn6<<<dim3(16, HDIM, BDIM), 512, 0, stream>>>(qkvb, hb);
    if (l < LNUM-1) {
      k_mlp<false><<<256, 1024, 0, stream>>>(
          hb, wpT + (size_t)l*65536, bp + l*CDIM,
          w1T + (size_t)l*65536, b1f + l*CDIM, w2T + (size_t)l*65536, b2 + l*CDIM,
          xb,
          wqkvT + (size_t)(l+1)*QSTR*256, bq + (l+1)*768, qkvb);
    } else {
      k_mlp<true><<<256, 1024, 0, stream>>>(
          hb, wpT + (size_t)l*65536, bp + l*CDIM,
          w1T + (size_t)l*65536, b1f + l*CDIM, w2T + (size_t)l*65536, b2 + l*CDIM,
          xb,
          wqkvT, bq, qkvb);
    }
  }
  k_poolln<<<32, 256, 0, stream>>>(xb, part);
  k_cls<<<1, 512, 0, stream>>>(part, Wc1s, bc1f, Wc2, bc2, (float*)d_out);
}

// Round 15
// 432.881 us; speedup vs baseline: 1.1761x; 1.0094x over previous
//
#include <hip/hip_runtime.h>
#include <hip/hip_bf16.h>

#define NTOK 8192      // B*T
#define CDIM 256
#define TDIM 2048
#define BDIM 4
#define HDIM 8
#define HSZ  32
#define LNUM 4
#define BUF  (NTOK*CDIM)
#define QSTR 768       // fused qkv row stride
#define LC   0.0901684400056f   // 2^-4 * log2(e), folded into Wq/bq

typedef __attribute__((ext_vector_type(8))) short short8v;
typedef __attribute__((ext_vector_type(4))) short short4v;
typedef __attribute__((ext_vector_type(4))) float float4v;

// ---- fp32 -> bf16 pack helpers ----
#if __has_builtin(__builtin_amdgcn_cvt_pk_bf16_f32)
static __device__ __forceinline__ unsigned pkbf(float a, float b){
  auto t = __builtin_amdgcn_cvt_pk_bf16_f32(a, b);
  union { decltype(t) v; unsigned u; } cv; cv.v = t;
  return cv.u;
}
static __device__ __forceinline__ short f2bs(float f){
  auto t = __builtin_amdgcn_cvt_pk_bf16_f32(f, f);
  union { decltype(t) v; unsigned u; } cv; cv.v = t;
  return (short)(cv.u & 0xFFFFu);
}
#else
static __device__ __forceinline__ short f2bs(float f){
  union { float f; unsigned u; } x; x.f = f;
  unsigned r = x.u + 0x7FFFu + ((x.u >> 16) & 1u);
  return (short)(r >> 16);
}
static __device__ __forceinline__ unsigned pkbf(float a, float b){
  union { float f; unsigned u; } x, y; x.f = a; y.f = b;
  unsigned ra = x.u + 0x7FFFu + ((x.u >> 16) & 1u);
  unsigned rb = y.u + 0x7FFFu + ((y.u >> 16) & 1u);
  return __builtin_amdgcn_perm(rb, ra, 0x07060302u);
}
#endif
#if __has_builtin(__builtin_amdgcn_exp2f)
static __device__ __forceinline__ float fexp2(float x){ return __builtin_amdgcn_exp2f(x); }
#else
static __device__ __forceinline__ float fexp2(float x){ return __expf(x*0.6931471805599453f); }
#endif

#if __has_builtin(__builtin_amdgcn_mfma_f32_16x16x16bf16_1k)
static __device__ __forceinline__ float4v mfma16(short4v a, short4v b, float4v c){
  return __builtin_amdgcn_mfma_f32_16x16x16bf16_1k(a, b, c, 0, 0, 0);
}
#else
static __device__ __forceinline__ float4v mfma16(short4v a, short4v b, float4v c){
  float4v d;
  asm volatile("v_mfma_f32_16x16x16_bf16 %0, %1, %2, %3\n\ts_nop 7\n\ts_nop 7"
               : "=v"(d) : "v"(a), "v"(b), "v"(c));
  return d;
}
#endif
static __device__ __forceinline__ float4v mfma32(short8v a, short8v b, float4v c){
  return __builtin_amdgcn_mfma_f32_16x16x32_bf16(a, b, c, 0, 0, 0);
}

// fragment-packed weight address: value (n,k) -> cg=n>>4, ks=k>>5, lane=((k>>3)&3)*16+(n&15), j=k&7
static __device__ __forceinline__ int faddr(int n, int k){
  return ((n>>4)*8 + (k>>5))*512 + ((((k>>3)&3)<<4) + (n&15))*8 + (k&7);
}

// ---------------- merged weight prep + bias folding + embedding + LN1(layer0) ----------------
__global__ __launch_bounds__(256) void k_prep_embed(
    const int* __restrict__ idx, const float* __restrict__ tok, const float* __restrict__ pos,
    const float* __restrict__ Wq, const float* __restrict__ Wk, const float* __restrict__ Wv,
    const float* __restrict__ Wp, const float* __restrict__ W1, const float* __restrict__ W2,
    const float* __restrict__ l1g, const float* __restrict__ l2g,
    const float* __restrict__ l1b, const float* __restrict__ l2b,
    const float* __restrict__ b1, const float* __restrict__ Wc1, const float* __restrict__ lnfg,
    const float* __restrict__ lnfb, const float* __restrict__ bc1,
    short* __restrict__ qkvT, short* __restrict__ wpT, short* __restrict__ w1T, short* __restrict__ w2T,
    float* __restrict__ bq, float* __restrict__ b1f, float* __restrict__ Wc1s, float* __restrict__ bc1f,
    float* __restrict__ x, short* __restrict__ y) {
  const int tid = threadIdx.x;
  const int id = blockIdx.x;
  if (id >= 513) {
    // ---- embedding + LN path ----
    const int bid = id - 513;
    const int lane = tid & 63;
    const int bt = bid*4 + (tid >> 6);
    const int t = bt & (TDIM-1);
    float4 tv = *(const float4*)&tok[(size_t)idx[bt]*CDIM + lane*4];
    float4 pv = *(const float4*)&pos[(size_t)t*CDIM + lane*4];
    float4 v = make_float4(tv.x+pv.x, tv.y+pv.y, tv.z+pv.z, tv.w+pv.w);
    *(float4*)&x[(size_t)bt*CDIM + lane*4] = v;
    float s1 = (v.x+v.y) + (v.z+v.w);
    float s2 = fmaf(v.x,v.x, fmaf(v.y,v.y, fmaf(v.z,v.z, v.w*v.w)));
    #pragma unroll
    for (int off=32; off>0; off>>=1) { s1 += __shfl_xor(s1, off, 64); s2 += __shfl_xor(s2, off, 64); }
    float mean = s1*(1.f/CDIM);
    float inv  = rsqrtf(s2*(1.f/CDIM) - mean*mean + 1e-5f);
    float cc = -mean*inv;
    union { unsigned u[2]; short4v s; } o;
    o.u[0] = pkbf(fmaf(v.x,inv,cc), fmaf(v.y,inv,cc));
    o.u[1] = pkbf(fmaf(v.z,inv,cc), fmaf(v.w,inv,cc));
    *(short4v*)&y[(size_t)bt*CDIM + lane*4] = o.s;
    return;
  }
  if (id < 384) {
    __shared__ float tile[64][65];
    int l = id / 96, rr = id % 96;
    const float* src; short* dst; int n0, k0; bool qkvmode; int gsel; float nscale = 1.f;
    if (rr < 48) {
      int tn = rr >> 2, tk = rr & 3;
      n0 = tn*64; k0 = tk*64;
      const float* b3 = (n0 < 256) ? Wq : (n0 < 512 ? Wk : Wv);
      src = b3 + l*65536;
      dst = qkvT + (size_t)l*QSTR*256;
      qkvmode = true; gsel = 1;
      if (n0 < 256) nscale = LC;
    } else {
      int r2 = rr - 48;
      int mat = r2 >> 4, t = r2 & 15;
      int tn = t >> 2, tk = t & 3;
      n0 = tn*64; k0 = tk*64;
      const float* b3 = (mat == 0) ? Wp : (mat == 1 ? W1 : W2);
      src = b3 + l*65536;
      dst = (mat == 0 ? wpT : (mat == 1 ? w1T : w2T)) + l*65536;
      qkvmode = false; gsel = (mat == 1) ? 2 : 0;
    }
    const int cn = tid & 63, rk = tid >> 6;
    #pragma unroll
    for (int i = 0; i < 16; ++i) {
      int kk = rk + i*4;
      int n = n0 + cn, k = k0 + kk;
      float v;
      if (qkvmode) { int nn = n & 255; v = src[((nn>>5)*256 + k)*32 + (nn & 31)]; }
      else         { v = src[k*256 + n]; }
      if (gsel == 1)      v *= l1g[l*256 + k];
      else if (gsel == 2) v *= l2g[l*256 + k];
      tile[kk][cn] = v;
    }
    __syncthreads();
    #pragma unroll
    for (int i = 0; i < 16; ++i) {
      int nn = rk + i*4;
      dst[faddr(n0 + nn, k0 + cn)] = f2bs(tile[cn][nn] * nscale);
    }
  } else if (id < 448) {
    __shared__ float red[4][64];
    int bid = id - 384;
    int l = bid >> 4, seg = bid & 15;
    int o = seg*64 + (tid & 63), pp = tid >> 6;
    float s = 0.f;
    if (o < 768) {
      const float* W = (o < 256 ? Wq : (o < 512 ? Wk : Wv)) + l*65536;
      int nn = o & 255, h = nn >> 5, d = nn & 31;
      const float* bv = l1b + l*256;
      for (int k = pp*64; k < pp*64+64; ++k) s = fmaf(bv[k], W[(h*256 + k)*32 + d], s);
    } else {
      const float* W = W1 + l*65536;
      int n = o - 768;
      const float* bv = l2b + l*256;
      for (int k = pp*64; k < pp*64+64; ++k) s = fmaf(bv[k], W[k*256 + n], s);
    }
    red[pp][tid & 63] = s;
    __syncthreads();
    if (tid < 64) {
      float tot = red[0][tid]+red[1][tid]+red[2][tid]+red[3][tid];
      int oo = seg*64 + tid;
      if (oo < 768) bq[l*768 + oo] = tot * (oo < 256 ? LC : 1.f);
      else          b1f[l*256 + (oo-768)] = b1[l*256 + (oo-768)] + tot;
    }
  } else if (id < 512) {
    int base = (id-448)*2048;
    #pragma unroll
    for (int i=0;i<8;++i) {
      int idx2 = base + i*256 + tid;
      Wc1s[idx2] = Wc1[idx2] * lnfg[idx2 >> 9];
    }
  } else {
    for (int u = tid; u < 512; u += 256) {
      float s = bc1[u];
      for (int k=0;k<256;++k) s = fmaf(lnfb[k], Wc1[k*512+u], s);
      bc1f[u] = s;
    }
  }
}

// ---------------- LDS-free MFMA GEMM (QKV layer 0): C = A(bf16) x Bfrag(packed) ----------------
template<int NF, bool BIAS, bool RELU, bool OUTBF16, bool ACCUM>
__global__ __launch_bounds__(64) void k_gemm3(const short* __restrict__ A,
    const short* __restrict__ Bt, const float* __restrict__ bias, void* __restrict__ Cv,
    int outstride) {
  const int lane = threadIdx.x;
  const int q4 = lane >> 4, r = lane & 15;
  const int blockRow = blockIdx.x * 32;
  const int blockCol = blockIdx.y * (NF*16);
  float4v acc[2][NF];
  #pragma unroll
  for (int i=0;i<2;++i)
    #pragma unroll
    for (int j=0;j<NF;++j) acc[i][j] = (float4v){0,0,0,0};
  #pragma unroll
  for (int k0 = 0; k0 < 256; k0 += 32) {
    short8v a0 = *(const short8v*)&A[(size_t)(blockRow +      r)*CDIM + k0 + q4*8];
    short8v a1 = *(const short8v*)&A[(size_t)(blockRow + 16 + r)*CDIM + k0 + q4*8];
    #pragma unroll
    for (int nf=0; nf<NF; ++nf) {
      short8v bf = *(const short8v*)&Bt[(size_t)(((blockCol>>4) + nf)*8 + (k0>>5))*512 + lane*8];
      acc[0][nf] = mfma32(a0, bf, acc[0][nf]);
      acc[1][nf] = mfma32(a1, bf, acc[1][nf]);
    }
  }
  #pragma unroll
  for (int mf=0; mf<2; ++mf)
    #pragma unroll
    for (int nf=0; nf<NF; ++nf) {
      int col = blockCol + nf*16 + r;
      float bb = BIAS ? bias[col] : 0.f;
      #pragma unroll
      for (int reg=0; reg<4; ++reg) {
        int row = blockRow + mf*16 + q4*4 + reg;
        float v = acc[mf][nf][reg] + bb;
        if (RELU) v = fmaxf(v, 0.f);
        size_t oi = (size_t)row*outstride + col;
        if (ACCUM)        ((float*)Cv)[oi] += v;
        else if (OUTBF16) ((short*)Cv)[oi] = f2bs(v);
        else              ((float*)Cv)[oi] = v;
      }
    }
}

// ---------------- fused per-layer MLP: proj+res+LN1 -> FFN -> res+LN2 -> next-layer QKV ------
template<bool LAST>
__global__ __launch_bounds__(1024, 4) void k_mlp(
    const short* __restrict__ A,            // attn output rows (bf16, stride CDIM)
    const short* __restrict__ Bt,           // wpT layer l (fragment-packed)
    const float* __restrict__ bias,         // bproj layer l
    const short* __restrict__ W1t, const float* __restrict__ b1f,
    const short* __restrict__ W2t, const float* __restrict__ b2,
    float* __restrict__ X,                  // fp32 residual stream
    const short* __restrict__ Wqkv,         // qkvT layer l+1 (fragment-packed; unused if LAST)
    const float* __restrict__ bq,           // bq layer l+1   (unused if LAST)
    short* __restrict__ Qout) {             // qkvb           (unused if LAST)
  __shared__ __align__(16) short Ys[32*264];
  __shared__ __align__(16) short Gs[32*264];
  __shared__ __align__(16) float S1[32][20], S2[32][20];   // 20-stride: bank-safe, float4-aligned
  const int tid = threadIdx.x;
  const int w = tid >> 6, lane = tid & 63;
  const int q4 = lane >> 4, r = lane & 15;
  const int row0 = blockIdx.x * 32;
  const int colw = w*16 + r;               // this wave's output column, phases A/B

  // ===== stage A tile (32x256 bf16 = 16KB) into Gs, fully coalesced =====
  {
    short8v av = *(const short8v*)&A[(size_t)row0*CDIM + tid*8];
    *(short8v*)&Gs[(tid>>5)*264 + (tid&31)*8] = av;
  }
  __syncthreads();

  // ===== Phase A: proj GEMM (A from LDS, B packed) =====
  float4v acc0 = {0,0,0,0}, acc1 = {0,0,0,0};
  #pragma unroll
  for (int k=0;k<8;++k) {
    short8v b  = *(const short8v*)&Bt[(size_t)(w*8+k)*512 + lane*8];
    short8v a0 = *(const short8v*)&Gs[(     r)*264 + k*32 + q4*8];
    short8v a1 = *(const short8v*)&Gs[(16 + r)*264 + k*32 + q4*8];
    acc0 = mfma32(a0, b, acc0);
    acc1 = mfma32(a1, b, acc1);
  }
  float xv0[4], xv1[4];
  {
    float bb = bias[colw];
    #pragma unroll
    for (int reg=0; reg<4; ++reg) {
      float t0 = acc0[reg] + bb + X[(size_t)(row0 +      q4*4 + reg)*CDIM + colw];
      float t1 = acc1[reg] + bb + X[(size_t)(row0 + 16 + q4*4 + reg)*CDIM + colw];
      xv0[reg] = t0; xv1[reg] = t1;
      float s10 = t0, s20 = t0*t0, s11 = t1, s21 = t1*t1;
      #pragma unroll
      for (int off=1; off<16; off<<=1) {
        s10 += __shfl_xor(s10, off, 64); s20 += __shfl_xor(s20, off, 64);
        s11 += __shfl_xor(s11, off, 64); s21 += __shfl_xor(s21, off, 64);
      }
      if (r == 0) {
        S1[     q4*4 + reg][w] = s10; S2[     q4*4 + reg][w] = s20;
        S1[16 + q4*4 + reg][w] = s11; S2[16 + q4*4 + reg][w] = s21;
      }
    }
  }
  __syncthreads();
  // LN1 -> Ys (vector reduce over 16 wave-partials)
  #pragma unroll
  for (int reg=0; reg<4; ++reg) {
    int r0i = q4*4 + reg, r1i = 16 + q4*4 + reg;
    float s1=0.f, s2=0.f, t1=0.f, t2=0.f;
    #pragma unroll
    for (int j4=0;j4<4;++j4) {
      float4 a1v = *(const float4*)&S1[r0i][j4*4];
      float4 a2v = *(const float4*)&S2[r0i][j4*4];
      float4 b1v = *(const float4*)&S1[r1i][j4*4];
      float4 b2v = *(const float4*)&S2[r1i][j4*4];
      s1 += (a1v.x+a1v.y)+(a1v.z+a1v.w);
      s2 += (a2v.x+a2v.y)+(a2v.z+a2v.w);
      t1 += (b1v.x+b1v.y)+(b1v.z+b1v.w);
      t2 += (b2v.x+b2v.y)+(b2v.z+b2v.w);
    }
    float mean = s1*(1.f/CDIM);
    float inv  = rsqrtf(s2*(1.f/CDIM) - mean*mean + 1e-5f);
    Ys[r0i*264 + colw] = f2bs(fmaf(xv0[reg], inv, -mean*inv));
    float mean2 = t1*(1.f/CDIM);
    float inv2  = rsqrtf(t2*(1.f/CDIM) - mean2*mean2 + 1e-5f);
    Ys[r1i*264 + colw] = f2bs(fmaf(xv1[reg], inv2, -mean2*inv2));
  }
  __syncthreads();

  // ===== FFN1: A from Ys, B packed -> relu -> Gs =====
  acc0 = (float4v){0,0,0,0}; acc1 = (float4v){0,0,0,0};
  #pragma unroll
  for (int k=0;k<8;++k) {
    short8v b  = *(const short8v*)&W1t[(size_t)(w*8+k)*512 + lane*8];
    short8v a0 = *(const short8v*)&Ys[(     r)*264 + k*32 + q4*8];
    short8v a1 = *(const short8v*)&Ys[(16 + r)*264 + k*32 + q4*8];
    acc0 = mfma32(a0, b, acc0);
    acc1 = mfma32(a1, b, acc1);
  }
  {
    float g = b1f[colw];
    #pragma unroll
    for (int reg=0; reg<4; ++reg) {
      Gs[(     q4*4 + reg)*264 + colw] = f2bs(fmaxf(acc0[reg] + g, 0.f));
      Gs[(16 + q4*4 + reg)*264 + colw] = f2bs(fmaxf(acc1[reg] + g, 0.f));
    }
  }
  __syncthreads();

  // ===== FFN2: A from Gs, B packed + residual [+ LN2 -> Ys] =====
  acc0 = (float4v){0,0,0,0}; acc1 = (float4v){0,0,0,0};
  #pragma unroll
  for (int k=0;k<8;++k) {
    short8v b  = *(const short8v*)&W2t[(size_t)(w*8+k)*512 + lane*8];
    short8v a0 = *(const short8v*)&Gs[(     r)*264 + k*32 + q4*8];
    short8v a1 = *(const short8v*)&Gs[(16 + r)*264 + k*32 + q4*8];
    acc0 = mfma32(a0, b, acc0);
    acc1 = mfma32(a1, b, acc1);
  }
  {
    float bb2 = b2[colw];
    #pragma unroll
    for (int reg=0; reg<4; ++reg) {
      float t0 = acc0[reg] + bb2 + xv0[reg];
      float t1 = acc1[reg] + bb2 + xv1[reg];
      xv0[reg] = t0; xv1[reg] = t1;
      X[(size_t)(row0 +      q4*4 + reg)*CDIM + colw] = t0;
      X[(size_t)(row0 + 16 + q4*4 + reg)*CDIM + colw] = t1;
      if (!LAST) {
        float s10 = t0, s20 = t0*t0, s11 = t1, s21 = t1*t1;
        #pragma unroll
        for (int off=1; off<16; off<<=1) {
          s10 += __shfl_xor(s10, off, 64); s20 += __shfl_xor(s20, off, 64);
          s11 += __shfl_xor(s11, off, 64); s21 += __shfl_xor(s21, off, 64);
        }
        if (r == 0) {
          S1[     q4*4 + reg][w] = s10; S2[     q4*4 + reg][w] = s20;
          S1[16 + q4*4 + reg][w] = s11; S2[16 + q4*4 + reg][w] = s21;
        }
      }
    }
  }
  if (LAST) return;
  __syncthreads();
  // LN2 -> Ys (vector reduce)
  #pragma unroll
  for (int reg=0; reg<4; ++reg) {
    int r0i = q4*4 + reg, r1i = 16 + q4*4 + reg;
    float s1=0.f, s2=0.f, t1=0.f, t2=0.f;
    #pragma unroll
    for (int j4=0;j4<4;++j4) {
      float4 a1v = *(const float4*)&S1[r0i][j4*4];
      float4 a2v = *(const float4*)&S2[r0i][j4*4];
      float4 b1v = *(const float4*)&S1[r1i][j4*4];
      float4 b2v = *(const float4*)&S2[r1i][j4*4];
      s1 += (a1v.x+a1v.y)+(a1v.z+a1v.w);
      s2 += (a2v.x+a2v.y)+(a2v.z+a2v.w);
      t1 += (b1v.x+b1v.y)+(b1v.z+b1v.w);
      t2 += (b2v.x+b2v.y)+(b2v.z+b2v.w);
    }
    float mean = s1*(1.f/CDIM);
    float inv  = rsqrtf(s2*(1.f/CDIM) - mean*mean + 1e-5f);
    Ys[r0i*264 + colw] = f2bs(fmaf(xv0[reg], inv, -mean*inv));
    float mean2 = t1*(1.f/CDIM);
    float inv2  = rsqrtf(t2*(1.f/CDIM) - mean2*mean2 + 1e-5f);
    Ys[r1i*264 + colw] = f2bs(fmaf(xv1[reg], inv2, -mean2*inv2));
  }
  __syncthreads();

  // ===== Phase C: next-layer QKV GEMM (A from Ys, B packed), wave = 32 rows x 48 cols =====
  {
    float4v qa0[3], qa1[3];
    #pragma unroll
    for (int j=0;j<3;++j) { qa0[j] = (float4v){0,0,0,0}; qa1[j] = (float4v){0,0,0,0}; }
    #pragma unroll
    for (int k=0;k<8;++k) {
      short8v ay0 = *(const short8v*)&Ys[(     r)*264 + k*32 + q4*8];
      short8v ay1 = *(const short8v*)&Ys[(16 + r)*264 + k*32 + q4*8];
      #pragma unroll
      for (int nf=0; nf<3; ++nf) {
        short8v b = *(const short8v*)&Wqkv[(size_t)((w*3+nf)*8 + k)*512 + lane*8];
        qa0[nf] = mfma32(ay0, b, qa0[nf]);
        qa1[nf] = mfma32(ay1, b, qa1[nf]);
      }
    }
    #pragma unroll
    for (int nf=0; nf<3; ++nf) {
      int col = (w*3+nf)*16 + r;
      float bb = bq[col];
      #pragma unroll
      for (int reg=0; reg<4; ++reg) {
        Qout[(size_t)(row0 +      q4*4 + reg)*QSTR + col] = f2bs(qa0[nf][reg] + bb);
        Qout[(size_t)(row0 + 16 + q4*4 + reg)*QSTR + col] = f2bs(qa1[nf][reg] + bb);
      }
    }
  }
}

// ---------------- MFMA flash attention: 128-key tiles, dbuf; l via ones-column MFMA ----------
#define KSS 40
#define VTS 140
__global__ __launch_bounds__(512) void k_attn6(const short* __restrict__ qkv,
    short* __restrict__ O) {
  __shared__ __align__(16) short Ks[2][128*KSS];
  __shared__ __align__(16) short Vt[2][32*VTS];
  const int tid = threadIdx.x;
  const int w = tid >> 6, lane = tid & 63;
  const int q4 = lane >> 4, r = lane & 15;
  const int b = blockIdx.z, h = blockIdx.y;
  const int rowbase = blockIdx.x*128 + w*16;
  short8v Qf = *(const short8v*)&qkv[((size_t)(b*TDIM + rowbase + r))*QSTR + h*HSZ + q4*8];
  float4v o0 = {0,0,0,0}, o1 = {0,0,0,0}, o2 = {0,0,0,0};
  const short ONE = (short)0x3F80;         // bf16 1.0
  const short4v ones = {ONE, ONE, ONE, ONE};
  const bool isV = tid >= 256;
  const int t2 = tid & 255;
  const int kkey = t2 >> 1, kd0 = (t2 & 1)*16;
  const int kp = t2 & 63, dg = t2 >> 6;
  const short* kvbase = qkv + (size_t)b*TDIM*QSTR + h*HSZ;
  short8v ka, kb2, va, vb;
  if (isV) {
    va = *(const short8v*)&kvbase[(size_t)(2*kp)*QSTR   + 2*CDIM + dg*8];
    vb = *(const short8v*)&kvbase[(size_t)(2*kp+1)*QSTR + 2*CDIM + dg*8];
  } else {
    ka  = *(const short8v*)&kvbase[(size_t)kkey*QSTR + CDIM + kd0];
    kb2 = *(const short8v*)&kvbase[(size_t)kkey*QSTR + CDIM + kd0 + 8];
  }
  int p = 0;
  for (int s0 = 0; s0 < TDIM; s0 += 128, p ^= 1) {
    if (isV) {
      union { short8v s; unsigned u[4]; } A, C;
      A.s = va; C.s = vb;
      #pragma unroll
      for (int j=0;j<4;++j) {
        *(unsigned*)&Vt[p][(dg*8+2*j  )*VTS + 2*kp] = __builtin_amdgcn_perm(C.u[j], A.u[j], 0x05040100u);
        *(unsigned*)&Vt[p][(dg*8+2*j+1)*VTS + 2*kp] = __builtin_amdgcn_perm(C.u[j], A.u[j], 0x07060302u);
      }
    } else {
      *(short8v*)&Ks[p][kkey*KSS + kd0]     = ka;
      *(short8v*)&Ks[p][kkey*KSS + kd0 + 8] = kb2;
    }
    if (s0 + 128 < TDIM) {
      const short* nb = kvbase + (size_t)(s0+128)*QSTR;
      if (isV) {
        va = *(const short8v*)&nb[(size_t)(2*kp)*QSTR   + 2*CDIM + dg*8];
        vb = *(const short8v*)&nb[(size_t)(2*kp+1)*QSTR + 2*CDIM + dg*8];
      } else {
        ka  = *(const short8v*)&nb[(size_t)kkey*QSTR + CDIM + kd0];
        kb2 = *(const short8v*)&nb[(size_t)kkey*QSTR + CDIM + kd0 + 8];
      }
    }
    __syncthreads();
    __builtin_amdgcn_s_setprio(1);
    #pragma unroll
    for (int ks = 0; ks < 8; ++ks) {
      short8v Kf = *(const short8v*)&Ks[p][(ks*16 + r)*KSS + q4*8];
      float4v sv = mfma32(Kf, Qf, (float4v){0,0,0,0});
      short4v Vf0 = *(const short4v*)&Vt[p][r*VTS + ks*16 + q4*4];
      short4v Vf1 = *(const short4v*)&Vt[p][(16+r)*VTS + ks*16 + q4*4];
      float p0 = fexp2(sv[0]), p1 = fexp2(sv[1]);
      float p2 = fexp2(sv[2]), p3 = fexp2(sv[3]);
      union { unsigned u[2]; short4v s; } P;
      P.u[0] = pkbf(p0, p1); P.u[1] = pkbf(p2, p3);
      o0 = mfma16(P.s, Vf0, o0);
      o1 = mfma16(P.s, Vf1, o1);
      o2 = mfma16(P.s, ones, o2);
    }
    __builtin_amdgcn_s_setprio(0);
  }
  #pragma unroll
  for (int reg=0; reg<4; ++reg) {
    float i0 = 1.f / o2[reg];
    short* op = O + ((size_t)(b*TDIM + rowbase + q4*4 + reg))*CDIM + h*HSZ;
    op[r]    = f2bs(o0[reg]*i0);
    op[16+r] = f2bs(o1[reg]*i0);
  }
}

// ---------------- fused final-LN + mean-pool ----------------
__global__ __launch_bounds__(256) void k_poolln(const float* __restrict__ X, float* __restrict__ part) {
  __shared__ float red[4][256];
  int b = blockIdx.x >> 3, chunk = blockIdx.x & 7;
  int wv = threadIdx.x >> 6, lane = threadIdx.x & 63;
  int base = b*TDIM + chunk*256 + wv*64;
  float a0=0,a1=0,a2=0,a3=0;
  for (int rr=0; rr<64; ++rr) {
    float4 v = *(const float4*)&X[(size_t)(base+rr)*CDIM + lane*4];
    float s1 = (v.x+v.y)+(v.z+v.w);
    float s2 = fmaf(v.x,v.x, fmaf(v.y,v.y, fmaf(v.z,v.z, v.w*v.w)));
    #pragma unroll
    for (int off=32; off>0; off>>=1) { s1 += __shfl_xor(s1,off,64); s2 += __shfl_xor(s2,off,64); }
    float mean = s1*(1.f/256.f);
    float inv  = rsqrtf(s2*(1.f/256.f) - mean*mean + 1e-5f);
    a0 = fmaf(v.x-mean, inv, a0); a1 = fmaf(v.y-mean, inv, a1);
    a2 = fmaf(v.z-mean, inv, a2); a3 = fmaf(v.w-mean, inv, a3);
  }
  red[wv][lane*4+0]=a0; red[wv][lane*4+1]=a1; red[wv][lane*4+2]=a2; red[wv][lane*4+3]=a3;
  __syncthreads();
  int c = threadIdx.x;
  part[blockIdx.x*256 + c] = (red[0][c]+red[1][c]+red[2][c]+red[3][c]) * (1.f/2048.f);
}

// ---------------- fused classifier ----------------
__global__ __launch_bounds__(512) void k_cls(const float* __restrict__ part,
    const float* __restrict__ Wc1s, const float* __restrict__ bc1f,
    const float* __restrict__ Wc2, const float* __restrict__ bc2, float* __restrict__ out) {
  __shared__ float se[4][256];
  __shared__ float sh[4][512];
  __shared__ float red[160];
  __shared__ float sl[40];
  const int t = threadIdx.x;
  for (int j=t; j<1024; j+=512) {
    int b = j >> 8, c = j & 255;
    float s = 0.f;
    #pragma unroll
    for (int ch=0; ch<8; ++ch) s += part[(b*8+ch)*256 + c];
    se[b][c] = s;
  }
  __syncthreads();
  {
    float bb = bc1f[t];
    float a0=bb, a1=bb, a2=bb, a3=bb;
    for (int c=0; c<256; ++c) {
      float w2 = Wc1s[c*512 + t];
      a0 = fmaf(se[0][c], w2, a0); a1 = fmaf(se[1][c], w2, a1);
      a2 = fmaf(se[2][c], w2, a2); a3 = fmaf(se[3][c], w2, a3);
    }
    sh[0][t]=fmaxf(a0,0.f); sh[1][t]=fmaxf(a1,0.f);
    sh[2][t]=fmaxf(a2,0.f); sh[3][t]=fmaxf(a3,0.f);
  }
  __syncthreads();
  if (t < 160) {
    int o = t >> 2, pp = t & 3;
    int b = o / 10, j = o - b*10;
    const float* hp = &sh[b][pp*128];
    float s = 0.f;
    #pragma unroll 8
    for (int u=0; u<128; ++u) s = fmaf(hp[u], Wc2[(pp*128+u)*10 + j], s);
    red[t] = s;
  }
  __syncthreads();
  if (t < 40) sl[t] = (red[t*4]+red[t*4+1]) + (red[t*4+2]+red[t*4+3]) + bc2[t%10];
  __syncthreads();
  if (t < 4) {
    float mx = -1e30f;
    for (int j=0;j<10;++j) mx = fmaxf(mx, sl[t*10+j]);
    float e[10], sum = 0.f;
    for (int j=0;j<10;++j) { e[j] = __expf(sl[t*10+j]-mx); sum += e[j]; }
    float inv = 1.f/sum;
    for (int j=0;j<10;++j) out[t*10+j] = e[j]*inv;
  }
}

extern "C" void kernel_launch(void* const* d_in, const int* in_sizes, int n_in,
                              void* d_out, int out_size, void* d_ws, size_t ws_size,
                              hipStream_t stream) {
  const int*   idx = (const int*)d_in[0];
  const float* tok = (const float*)d_in[1];
  const float* pos = (const float*)d_in[2];
  const float* Wq  = (const float*)d_in[3];
  const float* Wk  = (const float*)d_in[4];
  const float* Wv  = (const float*)d_in[5];
  const float* Wp  = (const float*)d_in[6];
  const float* bp  = (const float*)d_in[7];
  const float* l1g = (const float*)d_in[8];
  const float* l1b = (const float*)d_in[9];
  const float* l2g = (const float*)d_in[10];
  const float* l2b = (const float*)d_in[11];
  const float* W1  = (const float*)d_in[12];
  const float* b1  = (const float*)d_in[13];
  const float* W2  = (const float*)d_in[14];
  const float* b2  = (const float*)d_in[15];
  const float* lfg = (const float*)d_in[16];
  const float* lfb = (const float*)d_in[17];
  const float* Wc1 = (const float*)d_in[18];
  const float* bc1 = (const float*)d_in[19];
  const float* Wc2 = (const float*)d_in[20];
  const float* bc2 = (const float*)d_in[21];

  char* p = (char*)d_ws;
  float* xb   = (float*)p;              p += (size_t)BUF*4;
  short* hb   = (short*)p;              p += (size_t)BUF*2;
  short* qkvb = (short*)p;              p += (size_t)NTOK*QSTR*2;
  float* part = (float*)p;              p += 32*256*4;
  short* wqkvT = (short*)p;             p += (size_t)LNUM*QSTR*256*2;
  short* wpT   = (short*)p;             p += (size_t)LNUM*65536*2;
  short* w1T   = (short*)p;             p += (size_t)LNUM*65536*2;
  short* w2T   = (short*)p;             p += (size_t)LNUM*65536*2;
  float* bq    = (float*)p;             p += (size_t)LNUM*768*4;
  float* b1f   = (float*)p;             p += (size_t)LNUM*256*4;
  float* Wc1s  = (float*)p;             p += (size_t)256*512*4;
  float* bc1f  = (float*)p;             p += 512*4;

  k_prep_embed<<<513 + NTOK/4, 256, 0, stream>>>(idx, tok, pos,
                                   Wq, Wk, Wv, Wp, W1, W2, l1g, l2g, l1b, l2b,
                                   b1, Wc1, lfg, lfb, bc1,
                                   wqkvT, wpT, w1T, w2T, bq, b1f, Wc1s, bc1f,
                                   xb, hb);
  k_gemm3<4,true,false,true,false><<<dim3(256,12), 64, 0, stream>>>(
      hb, wqkvT, bq, qkvb, QSTR);
  for (int l = 0; l < LNUM; ++l) {
    k_attn6<<<dim3(16, HDIM, BDIM), 512, 0, stream>>>(qkvb, hb);
    if (l < LNUM-1) {
      k_mlp<false><<<256, 1024, 0, stream>>>(
          hb, wpT + (size_t)l*65536, bp + l*CDIM,
          w1T + (size_t)l*65536, b1f + l*CDIM, w2T + (size_t)l*65536, b2 + l*CDIM,
          xb,
          wqkvT + (size_t)(l+1)*QSTR*256, bq + (l+1)*768, qkvb);
    } else {
      k_mlp<true><<<256, 1024, 0, stream>>>(
          hb, wpT + (size_t)l*65536, bp + l*CDIM,
          w1T + (size_t)l*65536, b1f + l*CDIM, w2T + (size_t)l*65536, b2 + l*CDIM,
          xb,
          wqkvT, bq, qkvb);
    }
  }
  k_poolln<<<32, 256, 0, stream>>>(xb, part);
  k_cls<<<1, 512, 0, stream>>>(part, Wc1s, bc1f, Wc2, bc2, (float*)d_out);
}